// Round 4
// baseline (4069.051 us; speedup 1.0000x reference)
//
#include <hip/hip_runtime.h>
#include <stdint.h>

// ---------------------------------------------------------------------------
// Edgewise (eSCN SO(2) conv block), MI355X gfx950.
// Round 4: k_wig_fwd rebuilt as LDS-staged (coalesced float4 gather -> bf16
// LDS -> register compute). GEMM keeps m97 structure (global_load_lds,
// granule-swizzled LDS, pre-swizzled global source).
// ---------------------------------------------------------------------------

#define E_NUM   20000

typedef uint16_t u16;
typedef __bf16  bf16x8 __attribute__((ext_vector_type(8)));
typedef float   f32x4  __attribute__((ext_vector_type(4)));
typedef uint16_t u16x8 __attribute__((ext_vector_type(8)));
typedef uint16_t u16x4 __attribute__((ext_vector_type(4)));

__device__ __forceinline__ float bf2f(u16 h){
  uint32_t u = ((uint32_t)h) << 16;
  return __builtin_bit_cast(float, u);
}
__device__ __forceinline__ u16 f2bf(float f){
  uint32_t u = __builtin_bit_cast(uint32_t, f);
  u += 0x7fffu + ((u >> 16) & 1u);
  return (u16)(u >> 16);
}
__device__ __forceinline__ float sigm(float x){ return 1.f / (1.f + __expf(-x)); }

__device__ __forceinline__ void gload16(const void* g, void* l){
  __builtin_amdgcn_global_load_lds(
      (const __attribute__((address_space(1))) void*)g,
      (__attribute__((address_space(3))) void*)l, 16, 0, 0);
}

// --------------------------- weight transpose ------------------------------
__global__ void k_transpose_w(const float* __restrict__ in, u16* __restrict__ out,
                              int K, int N){
  __shared__ float t[32][33];
  int nb = blockIdx.x * 32, kb = blockIdx.y * 32;
  int tx = threadIdx.x & 31, ty = threadIdx.x >> 5;   // 32x8
  for (int i = ty; i < 32; i += 8)
    t[i][tx] = in[(size_t)(kb + i) * N + (nb + tx)];
  __syncthreads();
  for (int i = ty; i < 32; i += 8)
    out[(size_t)(nb + i) * K + (kb + tx)] = f2bf(t[tx][i]);
}

__global__ void k_f2bf(const float* __restrict__ in, u16* __restrict__ out, int n){
  int i = blockIdx.x * 256 + threadIdx.x;
  int stride = gridDim.x * 256;
  for (; i < n; i += stride) out[i] = f2bf(in[i]);
}

// ------------------------------- GEMM --------------------------------------
// C(M,N) = A(M,K) @ B^T, B given (N,K) bf16, both k-contiguous. m97 structure.
__global__ __launch_bounds__(256) void k_gemm_bt(
    const u16* __restrict__ A, int lda,
    const u16* __restrict__ B,
    const float* __restrict__ bias,
    float* __restrict__ Cf, u16* __restrict__ Cb, int ldc,
    int M, int N, int K)
{
  __shared__ u16 As[128 * 32];
  __shared__ u16 Bs[128 * 32];
  const int tid  = threadIdx.x;
  const int lane = tid & 63;
  const int wave = tid >> 6;
  const int wm = wave >> 1, wn = wave & 1;
  const int fr = lane & 15, fq = lane >> 4;
  const int bn = blockIdx.x, bm = blockIdx.y;
  const int row0 = bm * 128;

  // staging: lane i of each wave -> LDS row rb+(i>>2), granule (i&3).
  // LDS[r][g] holds global granule g^((r>>1)&3) of row r.
  const int lr  = lane >> 2;
  const int lg  = lane & 3;
  const int rA0 = wave * 32 + lr;
  const int rA1 = rA0 + 16;
  const int g0  = lg ^ ((rA0 >> 1) & 3);
  const int g1  = lg ^ ((rA1 >> 1) & 3);
  int gra0 = row0 + rA0; if (gra0 > M - 1) gra0 = M - 1;
  int gra1 = row0 + rA1; if (gra1 > M - 1) gra1 = M - 1;
  const u16* aS0 = A + (size_t)gra0 * lda + g0 * 8;
  const u16* aS1 = A + (size_t)gra1 * lda + g1 * 8;
  const u16* bS0 = B + (size_t)(bn * 128 + rA0) * K + g0 * 8;
  const u16* bS1 = B + (size_t)(bn * 128 + rA1) * K + g1 * 8;
  u16* aD0 = As + (wave * 32) * 32;
  u16* aD1 = As + (wave * 32 + 16) * 32;
  u16* bD0 = Bs + (wave * 32) * 32;
  u16* bD1 = Bs + (wave * 32 + 16) * 32;

  const u16* afp[4]; const u16* bfp[4];
  #pragma unroll
  for (int mi = 0; mi < 4; ++mi){
    int r = wm * 64 + mi * 16 + fr;
    afp[mi] = As + r * 32 + (fq ^ ((r >> 1) & 3)) * 8;
  }
  #pragma unroll
  for (int ni = 0; ni < 4; ++ni){
    int r = wn * 64 + ni * 16 + fr;
    bfp[ni] = Bs + r * 32 + (fq ^ ((r >> 1) & 3)) * 8;
  }

  f32x4 acc[4][4];
  #pragma unroll
  for (int i = 0; i < 4; ++i)
    #pragma unroll
    for (int j = 0; j < 4; ++j) acc[i][j] = (f32x4){0.f, 0.f, 0.f, 0.f};

  for (int k0 = 0; k0 < K; k0 += 32){
    gload16(aS0 + k0, aD0);
    gload16(aS1 + k0, aD1);
    gload16(bS0 + k0, bD0);
    gload16(bS1 + k0, bD1);
    __syncthreads();
    bf16x8 af[4], bfv[4];
    #pragma unroll
    for (int mi = 0; mi < 4; ++mi)
      af[mi] = __builtin_bit_cast(bf16x8, *(const u16x8*)afp[mi]);
    #pragma unroll
    for (int ni = 0; ni < 4; ++ni)
      bfv[ni] = __builtin_bit_cast(bf16x8, *(const u16x8*)bfp[ni]);
    #pragma unroll
    for (int mi = 0; mi < 4; ++mi)
      #pragma unroll
      for (int ni = 0; ni < 4; ++ni)
        acc[mi][ni] = __builtin_amdgcn_mfma_f32_16x16x32_bf16(af[mi], bfv[ni], acc[mi][ni], 0, 0, 0);
    __syncthreads();
  }

  #pragma unroll
  for (int ni = 0; ni < 4; ++ni){
    int col = bn * 128 + wn * 64 + ni * 16 + fr;
    float bv = bias ? bias[col] : 0.f;
    #pragma unroll
    for (int mi = 0; mi < 4; ++mi){
      #pragma unroll
      for (int i = 0; i < 4; ++i){
        int row = row0 + wm * 64 + mi * 16 + fq * 4 + i;
        if (row < M){
          float v = acc[mi][ni][i] + bv;
          if (Cb) Cb[(size_t)row * ldc + col] = f2bf(v);
          else    Cf[(size_t)row * ldc + col] = v;
        }
      }
    }
  }
}

// --------------------------- LayerNorm + SiLU ------------------------------
__global__ __launch_bounds__(256) void k_ln_silu(
    const float* __restrict__ in, const float* __restrict__ sc,
    const float* __restrict__ bb, u16* __restrict__ out)
{
  int e = blockIdx.x, t = threadIdx.x;
  float v = in[(size_t)e * 256 + t];
  float s1 = v, s2 = v * v;
  #pragma unroll
  for (int off = 32; off > 0; off >>= 1){
    s1 += __shfl_down(s1, off);
    s2 += __shfl_down(s2, off);
  }
  __shared__ float r1[4], r2[4];
  if ((t & 63) == 0){ r1[t >> 6] = s1; r2[t >> 6] = s2; }
  __syncthreads();
  float S1 = r1[0] + r1[1] + r1[2] + r1[3];
  float S2 = r2[0] + r2[1] + r2[2] + r2[3];
  float mu  = S1 * (1.f / 256.f);
  float var = S2 * (1.f / 256.f) - mu * mu;
  float nv = (v - mu) * rsqrtf(var + 1e-5f) * sc[t] + bb[t];
  out[(size_t)e * 256 + t] = f2bf(nv * sigm(nv));
}

// --------------------- Wigner forward (gather+scale) -----------------------
// LDS-staged: coalesced float4 loads of both node rows -> bf16 LDS (25 KB),
// then per-thread m-outer compute with xv[49] in registers; fused xrad scale.
__global__ __launch_bounds__(256) void k_wig_fwd(
    const float* __restrict__ x, const int* __restrict__ eidx,
    const float* __restrict__ wig, const u16* __restrict__ xrad,
    u16* __restrict__ msgS, int e0)
{
  __shared__ u16 xl[2 * 6272];
  int el = blockIdx.x, tid = threadIdx.x;
  int eg = e0 + el;
  int n0 = eidx[eg];
  int n1 = eidx[E_NUM + eg];
  const float* p0 = x + (size_t)n0 * 6272;
  const float* p1 = x + (size_t)n1 * 6272;
  // stage both rows: 2 * 1568 float4
  for (int i = tid; i < 3136; i += 256){
    int node = (i >= 1568);
    int li = i - (node << 10) - (node << 9) - (node << 5);  // i - node*1568
    f32x4 v = *(const f32x4*)((node ? p1 : p0) + (size_t)li * 4);
    u16x4 h;
    h[0] = f2bf(v[0]); h[1] = f2bf(v[1]); h[2] = f2bf(v[2]); h[3] = f2bf(v[3]);
    *(u16x4*)(&xl[node * 6272 + li * 4]) = h;
  }
  __syncthreads();

  const int half = tid >> 7, ch = tid & 127;
  const u16* xs = xl + half * 6272 + ch;
  float xv[49];
  #pragma unroll
  for (int j = 0; j < 49; ++j) xv[j] = bf2f(xs[j * 128]);

  const float* w = wig + (size_t)eg * 1421;      // block-uniform -> s_loads
  const u16* xr = xrad + (size_t)el * 4608 + tid;
  u16* o = msgS + (size_t)el * 7424 + tid;
  #pragma unroll
  for (int m = 0; m < 29; ++m){
    float a = 0.f;
    #pragma unroll
    for (int j = 0; j < 49; ++j) a = fmaf(w[m * 49 + j], xv[j], a);
    int rr = (m < 13) ? m : (m < 24 ? m - 6 : m - 11);
    o[m * 256] = f2bf(a * bf2f(xr[rr * 256]));
  }
}

// ------------------------ gate + recombine (conv1) -------------------------
__global__ __launch_bounds__(128) void k_gate(
    const u16* __restrict__ c1m0, const u16* __restrict__ y10, const u16* __restrict__ y11,
    const u16* __restrict__ y20, const u16* __restrict__ y21, u16* __restrict__ msg2)
{
  int e = blockIdx.x, c = threadIdx.x;
  __shared__ float g[768];
  const u16* gp = c1m0 + (size_t)e * 1664;
  for (int i = c; i < 768; i += 128) g[i] = sigm(bf2f(gp[i]));
  __syncthreads();
  const u16* x0 = gp + 768;
  u16* o = msg2 + (size_t)e * 3712;
  { float v = bf2f(x0[c]); o[c] = f2bf(v * sigm(v)); }
  #pragma unroll
  for (int r = 1; r < 7; ++r)
    o[r * 128 + c] = f2bf(bf2f(x0[r * 128 + c]) * g[(r - 1) * 128 + c]);
  const u16* a0 = y10 + (size_t)e * 1536;
  const u16* a1 = y11 + (size_t)e * 1536;
  #pragma unroll
  for (int k = 0; k < 6; ++k){
    float orr = bf2f(a0[k * 128 + c]) - bf2f(a1[768 + k * 128 + c]);
    float oii = bf2f(a1[k * 128 + c]) + bf2f(a0[768 + k * 128 + c]);
    float gv = g[k * 128 + c];
    o[(7 + k)  * 128 + c] = f2bf(orr * gv);
    o[(13 + k) * 128 + c] = f2bf(oii * gv);
  }
  const u16* b0 = y20 + (size_t)e * 1280;
  const u16* b1 = y21 + (size_t)e * 1280;
  #pragma unroll
  for (int k = 0; k < 5; ++k){
    float orr = bf2f(b0[k * 128 + c]) - bf2f(b1[640 + k * 128 + c]);
    float oii = bf2f(b1[k * 128 + c]) + bf2f(b0[640 + k * 128 + c]);
    float gv = g[(1 + k) * 128 + c];
    o[(19 + k) * 128 + c] = f2bf(orr * gv);
    o[(24 + k) * 128 + c] = f2bf(oii * gv);
  }
}

// --------------------- recombine2 + envelope (conv2) -----------------------
__global__ __launch_bounds__(128) void k_recomb2(
    const u16* __restrict__ m3x0, const u16* __restrict__ z10, const u16* __restrict__ z11,
    const u16* __restrict__ z20, const u16* __restrict__ z21, const float* __restrict__ env,
    u16* __restrict__ msg3)
{
  int e = blockIdx.x, c = threadIdx.x;
  float ev = env[e];
  const u16* x0 = m3x0 + (size_t)e * 896;
  u16* o = msg3 + (size_t)e * 3712;
  #pragma unroll
  for (int r = 0; r < 7; ++r) o[r * 128 + c] = f2bf(bf2f(x0[r * 128 + c]) * ev);
  const u16* a0 = z10 + (size_t)e * 1536;
  const u16* a1 = z11 + (size_t)e * 1536;
  #pragma unroll
  for (int k = 0; k < 6; ++k){
    float orr = bf2f(a0[k * 128 + c]) - bf2f(a1[768 + k * 128 + c]);
    float oii = bf2f(a1[k * 128 + c]) + bf2f(a0[768 + k * 128 + c]);
    o[(7 + k)  * 128 + c] = f2bf(orr * ev);
    o[(13 + k) * 128 + c] = f2bf(oii * ev);
  }
  const u16* b0 = z20 + (size_t)e * 1280;
  const u16* b1 = z21 + (size_t)e * 1280;
  #pragma unroll
  for (int k = 0; k < 5; ++k){
    float orr = bf2f(b0[k * 128 + c]) - bf2f(b1[640 + k * 128 + c]);
    float oii = bf2f(b1[k * 128 + c]) + bf2f(b0[640 + k * 128 + c]);
    o[(19 + k) * 128 + c] = f2bf(orr * ev);
    o[(24 + k) * 128 + c] = f2bf(oii * ev);
  }
}

// -------------------- Wigner inverse + scatter-add -------------------------
__global__ __launch_bounds__(256) void k_wig_inv(
    const u16* __restrict__ msg3, const float* __restrict__ winv,
    const int* __restrict__ eidx, float* __restrict__ out, int e0)
{
  int el = blockIdx.x, t = threadIdx.x;
  int c = t & 127, jh = t >> 7;
  int eg = e0 + el;
  const u16* mp = msg3 + (size_t)el * 3712 + c;
  float vm[29];
  #pragma unroll
  for (int m = 0; m < 29; ++m) vm[m] = bf2f(mp[m * 128]);
  const float* w = winv + (size_t)eg * 1421;   // uniform -> s_loads
  int dst = eidx[E_NUM + eg];
  float* op = out + (size_t)dst * 6272 + c;
  int j0 = jh * 25, jend = jh ? 49 : 25;
  for (int j = j0; j < jend; ++j){
    float a = 0.f;
    #pragma unroll
    for (int m = 0; m < 29; ++m) a = fmaf(w[j * 29 + m], vm[m], a);
    atomicAdd(op + (size_t)j * 128, a);
  }
}

// ---------------------------------------------------------------------------
extern "C" void kernel_launch(void* const* d_in, const int* in_sizes, int n_in,
                              void* d_out, int out_size, void* d_ws, size_t ws_size,
                              hipStream_t stream)
{
  (void)in_sizes; (void)n_in;
  const float* x       = (const float*)d_in[0];
  const float* x_edge  = (const float*)d_in[1];
  const int*   eidx    = (const int*)d_in[3];
  const float* wig     = (const float*)d_in[4];
  const float* wig_inv = (const float*)d_in[5];
  const float* env     = (const float*)d_in[6];
  const float* rad_w0  = (const float*)d_in[7];
  const float* rad_b0  = (const float*)d_in[8];
  const float* ln0_s   = (const float*)d_in[9];
  const float* ln0_b   = (const float*)d_in[10];
  const float* rad_w1  = (const float*)d_in[11];
  const float* rad_b1  = (const float*)d_in[12];
  const float* ln1_s   = (const float*)d_in[13];
  const float* ln1_b   = (const float*)d_in[14];
  const float* rad_w2  = (const float*)d_in[15];
  const float* rad_b2  = (const float*)d_in[16];
  const float* c1w0    = (const float*)d_in[17];
  const float* c1b0    = (const float*)d_in[18];
  const float* c1w1    = (const float*)d_in[19];
  const float* c1w2    = (const float*)d_in[20];
  const float* c2w0    = (const float*)d_in[21];
  const float* c2b0    = (const float*)d_in[22];
  const float* c2w1    = (const float*)d_in[23];
  const float* c2w2    = (const float*)d_in[24];
  float* out = (float*)d_out;

  char* base = (char*)d_ws;
  size_t off = 0;
  auto alloc = [&](size_t bytes) -> char* {
    off = (off + 255) & ~(size_t)255;
    char* r = base + off;
    off += bytes;
    return r;
  };

  // ---- fixed area: transposed bf16 weights (~22.2 MB) ----
  u16* wtR0  = (u16*)alloc((size_t)256  * 128  * 2);
  u16* wtR1  = (u16*)alloc((size_t)256  * 256  * 2);
  u16* wtR2  = (u16*)alloc((size_t)4608 * 256  * 2);
  u16* wtC10 = (u16*)alloc((size_t)1664 * 1792 * 2);
  u16* wtC11 = (u16*)alloc((size_t)1536 * 1536 * 2);
  u16* wtC12 = (u16*)alloc((size_t)1280 * 1280 * 2);
  u16* wtC20 = (u16*)alloc((size_t)896  * 896  * 2);
  u16* wtC21 = (u16*)alloc((size_t)1536 * 768  * 2);
  u16* wtC22 = (u16*)alloc((size_t)1280 * 640  * 2);

  // ---- chunk size from remaining workspace (40,960 B per edge) ----
  size_t fixed_end = (off + 65536) & ~(size_t)65535;
  size_t avail = (ws_size > fixed_end + (1u << 20)) ? (ws_size - fixed_end - (1u << 20)) : 0;
  int CH = (int)(avail / 40960);
  if (CH > 5000) CH = 5000;
  CH &= ~63;
  if (CH < 64) CH = 64;

  off = fixed_end;
  const size_t C = (size_t)CH;
  u16*   xe   = (u16*)alloc(C * 128 * 2);
  float* tmp  = (float*)alloc(C * 256 * 4);
  u16*   h0   = (u16*)alloc(C * 256 * 2);
  u16*   h1   = (u16*)alloc(C * 256 * 2);
  u16* region1 = (u16*)alloc(C * 4608 * 2);   // xrad -> msg2
  u16* region2 = (u16*)alloc(C * 7424 * 2);   // msgS -> conv2 outs
  u16* region3 = (u16*)alloc(C * 7296 * 2);   // conv1 outs -> msg3
  u16* xrad = region1;
  u16* msg2 = region1;
  u16* msgS = region2;
  u16* m3x0 = region2;                 // (C,896)
  u16* z10  = region2 + C * 896;       // (C,1536)
  u16* z11  = region2 + C * 2432;      // (C,1536)
  u16* z20  = region2 + C * 3968;      // (C,1280)
  u16* z21  = region2 + C * 5248;      // (C,1280)
  u16* c1m0b = region3;                // (C,1664)
  u16* y10   = region3 + C * 1664;     // (C,1536)
  u16* y11   = region3 + C * 3200;     // (C,1536)
  u16* y20   = region3 + C * 4736;     // (C,1280)
  u16* y21   = region3 + C * 6016;     // (C,1280)
  u16* msg3  = region3;                // (C,3712)

  hipMemsetAsync(d_out, 0, (size_t)out_size * sizeof(float), stream);

  auto tw = [&](const float* in, u16* o, int K, int N){
    k_transpose_w<<<dim3(N / 32, K / 32), 256, 0, stream>>>(in, o, K, N);
  };
  tw(rad_w0, wtR0, 128, 256);
  tw(rad_w1, wtR1, 256, 256);
  tw(rad_w2, wtR2, 256, 4608);
  tw(c1w0, wtC10, 1792, 1664);
  tw(c1w1, wtC11, 1536, 1536);
  tw(c1w2, wtC12, 1280, 1280);
  tw(c2w0, wtC20, 896, 896);
  tw(c2w1, wtC21, 768, 1536);
  tw(c2w2, wtC22, 640, 1280);

  auto gemm = [&](const u16* A, int lda, const u16* B, const float* bias,
                  float* Cf, u16* Cb, int ldc, int M, int N, int K){
    k_gemm_bt<<<dim3(N / 128, (M + 127) / 128), 256, 0, stream>>>(
        A, lda, B, bias, Cf, Cb, ldc, M, N, K);
  };

  for (int e0 = 0; e0 < E_NUM; e0 += CH){
    int cm = E_NUM - e0 < CH ? E_NUM - e0 : CH;

    k_f2bf<<<(cm * 128 + 255) / 256, 256, 0, stream>>>(x_edge + (size_t)e0 * 128, xe, cm * 128);

    // radial MLP
    gemm(xe, 128, wtR0, rad_b0, tmp, nullptr, 256, cm, 256, 128);
    k_ln_silu<<<cm, 256, 0, stream>>>(tmp, ln0_s, ln0_b, h0);
    gemm(h0, 256, wtR1, rad_b1, tmp, nullptr, 256, cm, 256, 256);
    k_ln_silu<<<cm, 256, 0, stream>>>(tmp, ln1_s, ln1_b, h1);
    gemm(h1, 256, wtR2, rad_b2, nullptr, xrad, 4608, cm, 4608, 256);

    // wigner forward + gather + radial scale
    k_wig_fwd<<<cm, 256, 0, stream>>>(x, eidx, wig, xrad, msgS, e0);

    // conv1
    gemm(msgS,        7424, wtC10, c1b0,    nullptr, c1m0b, 1664, cm, 1664, 1792);
    gemm(msgS + 1792, 7424, wtC11, nullptr, nullptr, y10,  1536, cm, 1536, 1536);
    gemm(msgS + 3328, 7424, wtC11, nullptr, nullptr, y11,  1536, cm, 1536, 1536);
    gemm(msgS + 4864, 7424, wtC12, nullptr, nullptr, y20,  1280, cm, 1280, 1280);
    gemm(msgS + 6144, 7424, wtC12, nullptr, nullptr, y21,  1280, cm, 1280, 1280);

    k_gate<<<cm, 128, 0, stream>>>(c1m0b, y10, y11, y20, y21, msg2);

    // conv2
    gemm(msg2,        3712, wtC20, c2b0,    nullptr, m3x0, 896,  cm, 896,  896);
    gemm(msg2 + 896,  3712, wtC21, nullptr, nullptr, z10, 1536, cm, 1536, 768);
    gemm(msg2 + 1664, 3712, wtC21, nullptr, nullptr, z11, 1536, cm, 1536, 768);
    gemm(msg2 + 2432, 3712, wtC22, nullptr, nullptr, z20, 1280, cm, 1280, 640);
    gemm(msg2 + 3072, 3712, wtC22, nullptr, nullptr, z21, 1280, cm, 1280, 640);

    k_recomb2<<<cm, 128, 0, stream>>>(m3x0, z10, z11, z20, z21, env + e0, msg3);

    // wigner inverse + scatter
    k_wig_inv<<<cm, 256, 0, stream>>>(msg3, wig_inv, eidx, out, e0);
  }
}

// Round 5
// 3356.792 us; speedup vs baseline: 1.2122x; 1.2122x over previous
//
#include <hip/hip_runtime.h>
#include <stdint.h>

// ---------------------------------------------------------------------------
// Edgewise (eSCN SO(2) conv block), MI355X gfx950.
// Round 5: Wigner fwd/inv rebuilt as MFMA kernels (w/winv via vector loads ->
// LDS, X^T swizzled LDS for B-operand; msg3 stored transposed so wig_inv's
// B-operand is a coalesced global b128 read). GEMM keeps m97 structure.
// ---------------------------------------------------------------------------

#define E_NUM   20000

typedef uint16_t u16;
typedef __bf16  bf16x8 __attribute__((ext_vector_type(8)));
typedef float   f32x4  __attribute__((ext_vector_type(4)));
typedef uint16_t u16x8 __attribute__((ext_vector_type(8)));

__device__ __forceinline__ float bf2f(u16 h){
  uint32_t u = ((uint32_t)h) << 16;
  return __builtin_bit_cast(float, u);
}
__device__ __forceinline__ u16 f2bf(float f){
  uint32_t u = __builtin_bit_cast(uint32_t, f);
  u += 0x7fffu + ((u >> 16) & 1u);
  return (u16)(u >> 16);
}
__device__ __forceinline__ float sigm(float x){ return 1.f / (1.f + __expf(-x)); }

__device__ __forceinline__ void gload16(const void* g, void* l){
  __builtin_amdgcn_global_load_lds(
      (const __attribute__((address_space(1))) void*)g,
      (__attribute__((address_space(3))) void*)l, 16, 0, 0);
}

// --------------------------- weight transpose ------------------------------
__global__ void k_transpose_w(const float* __restrict__ in, u16* __restrict__ out,
                              int K, int N){
  __shared__ float t[32][33];
  int nb = blockIdx.x * 32, kb = blockIdx.y * 32;
  int tx = threadIdx.x & 31, ty = threadIdx.x >> 5;   // 32x8
  for (int i = ty; i < 32; i += 8)
    t[i][tx] = in[(size_t)(kb + i) * N + (nb + tx)];
  __syncthreads();
  for (int i = ty; i < 32; i += 8)
    out[(size_t)(nb + i) * K + (kb + tx)] = f2bf(t[tx][i]);
}

__global__ void k_f2bf(const float* __restrict__ in, u16* __restrict__ out, int n){
  int i = blockIdx.x * 256 + threadIdx.x;
  int stride = gridDim.x * 256;
  for (; i < n; i += stride) out[i] = f2bf(in[i]);
}

// ------------------------------- GEMM --------------------------------------
// C(M,N) = A(M,K) @ B^T, B given (N,K) bf16, both k-contiguous. m97 structure.
__global__ __launch_bounds__(256) void k_gemm_bt(
    const u16* __restrict__ A, int lda,
    const u16* __restrict__ B,
    const float* __restrict__ bias,
    float* __restrict__ Cf, u16* __restrict__ Cb, int ldc,
    int M, int N, int K)
{
  __shared__ u16 As[128 * 32];
  __shared__ u16 Bs[128 * 32];
  const int tid  = threadIdx.x;
  const int lane = tid & 63;
  const int wave = tid >> 6;
  const int wm = wave >> 1, wn = wave & 1;
  const int fr = lane & 15, fq = lane >> 4;
  const int bn = blockIdx.x, bm = blockIdx.y;
  const int row0 = bm * 128;

  const int lr  = lane >> 2;
  const int lg  = lane & 3;
  const int rA0 = wave * 32 + lr;
  const int rA1 = rA0 + 16;
  const int g0  = lg ^ ((rA0 >> 1) & 3);
  const int g1  = lg ^ ((rA1 >> 1) & 3);
  int gra0 = row0 + rA0; if (gra0 > M - 1) gra0 = M - 1;
  int gra1 = row0 + rA1; if (gra1 > M - 1) gra1 = M - 1;
  const u16* aS0 = A + (size_t)gra0 * lda + g0 * 8;
  const u16* aS1 = A + (size_t)gra1 * lda + g1 * 8;
  const u16* bS0 = B + (size_t)(bn * 128 + rA0) * K + g0 * 8;
  const u16* bS1 = B + (size_t)(bn * 128 + rA1) * K + g1 * 8;
  u16* aD0 = As + (wave * 32) * 32;
  u16* aD1 = As + (wave * 32 + 16) * 32;
  u16* bD0 = Bs + (wave * 32) * 32;
  u16* bD1 = Bs + (wave * 32 + 16) * 32;

  const u16* afp[4]; const u16* bfp[4];
  #pragma unroll
  for (int mi = 0; mi < 4; ++mi){
    int r = wm * 64 + mi * 16 + fr;
    afp[mi] = As + r * 32 + (fq ^ ((r >> 1) & 3)) * 8;
  }
  #pragma unroll
  for (int ni = 0; ni < 4; ++ni){
    int r = wn * 64 + ni * 16 + fr;
    bfp[ni] = Bs + r * 32 + (fq ^ ((r >> 1) & 3)) * 8;
  }

  f32x4 acc[4][4];
  #pragma unroll
  for (int i = 0; i < 4; ++i)
    #pragma unroll
    for (int j = 0; j < 4; ++j) acc[i][j] = (f32x4){0.f, 0.f, 0.f, 0.f};

  for (int k0 = 0; k0 < K; k0 += 32){
    gload16(aS0 + k0, aD0);
    gload16(aS1 + k0, aD1);
    gload16(bS0 + k0, bD0);
    gload16(bS1 + k0, bD1);
    __syncthreads();
    bf16x8 af[4], bfv[4];
    #pragma unroll
    for (int mi = 0; mi < 4; ++mi)
      af[mi] = __builtin_bit_cast(bf16x8, *(const u16x8*)afp[mi]);
    #pragma unroll
    for (int ni = 0; ni < 4; ++ni)
      bfv[ni] = __builtin_bit_cast(bf16x8, *(const u16x8*)bfp[ni]);
    #pragma unroll
    for (int mi = 0; mi < 4; ++mi)
      #pragma unroll
      for (int ni = 0; ni < 4; ++ni)
        acc[mi][ni] = __builtin_amdgcn_mfma_f32_16x16x32_bf16(af[mi], bfv[ni], acc[mi][ni], 0, 0, 0);
    __syncthreads();
  }

  #pragma unroll
  for (int ni = 0; ni < 4; ++ni){
    int col = bn * 128 + wn * 64 + ni * 16 + fr;
    float bv = bias ? bias[col] : 0.f;
    #pragma unroll
    for (int mi = 0; mi < 4; ++mi){
      #pragma unroll
      for (int i = 0; i < 4; ++i){
        int row = row0 + wm * 64 + mi * 16 + fq * 4 + i;
        if (row < M){
          float v = acc[mi][ni][i] + bv;
          if (Cb) Cb[(size_t)row * ldc + col] = f2bf(v);
          else    Cf[(size_t)row * ldc + col] = v;
        }
      }
    }
  }
}

// --------------------------- LayerNorm + SiLU ------------------------------
__global__ __launch_bounds__(256) void k_ln_silu(
    const float* __restrict__ in, const float* __restrict__ sc,
    const float* __restrict__ bb, u16* __restrict__ out)
{
  int e = blockIdx.x, t = threadIdx.x;
  float v = in[(size_t)e * 256 + t];
  float s1 = v, s2 = v * v;
  #pragma unroll
  for (int off = 32; off > 0; off >>= 1){
    s1 += __shfl_down(s1, off);
    s2 += __shfl_down(s2, off);
  }
  __shared__ float r1[4], r2[4];
  if ((t & 63) == 0){ r1[t >> 6] = s1; r2[t >> 6] = s2; }
  __syncthreads();
  float S1 = r1[0] + r1[1] + r1[2] + r1[3];
  float S2 = r2[0] + r2[1] + r2[2] + r2[3];
  float mu  = S1 * (1.f / 256.f);
  float var = S2 * (1.f / 256.f) - mu * mu;
  float nv = (v - mu) * rsqrtf(var + 1e-5f) * sc[t] + bb[t];
  out[(size_t)e * 256 + t] = f2bf(nv * sigm(nv));
}

// --------------------- Wigner forward (MFMA) -------------------------------
// msg[m][c] = (sum_k W[m][k] X[k][c]) * xrad, per edge.
// X^T staged in LDS: elem (c,k) at c*64 + ((k>>3)^(c&7))*8 + (k&7)  (32 KB)
// W  staged in LDS: elem (m,k) at m*64 + ((k>>3)^(m&7))*8 + (k&7)   (4 KB)
// Both operands then read k-contiguous b128 exactly like the verified GEMM.
__global__ __launch_bounds__(256) void k_wig_fwd(
    const float* __restrict__ x, const int* __restrict__ eidx,
    const float* __restrict__ wig, const u16* __restrict__ xrad,
    u16* __restrict__ msgS, int e0)
{
  __shared__ u16 XT[256 * 64];
  __shared__ u16 WL[32 * 64];
  int el = blockIdx.x, tid = threadIdx.x;
  int eg = e0 + el;
  int lane = tid & 63, w = tid >> 6;

  // stage W (pad m>=29, k>=49 with zeros)
  const float* wp = wig + (size_t)eg * 1421;
  for (int idx = tid; idx < 2048; idx += 256){
    int m = idx >> 6, k = idx & 63;
    float v = (m < 29 && k < 49) ? wp[m * 49 + k] : 0.f;
    WL[m * 64 + ((((k >> 3) ^ (m & 7))) << 3) + (k & 7)] = f2bf(v);
  }

  // stage X^T: wave w owns XT cols w*64..w*64+63 (node = w>>1, xcol = (w&1)*64+lane)
  int node = eidx[((w >> 1) ? E_NUM : 0) + eg];
  const float* xp = x + (size_t)node * 6272 + ((w & 1) * 64 + lane);
  int xtc = w * 64 + lane;
  u16* xtp = &XT[xtc * 64];
  const int cs = (xtc & 7) << 3;
  #pragma unroll
  for (int g = 0; g < 8; ++g){
    u16x8 h = {0,0,0,0,0,0,0,0};
    #pragma unroll
    for (int i = 0; i < 8; ++i){
      int k = g * 8 + i;
      if (k < 49) h[i] = f2bf(xp[k * 128]);
    }
    *(u16x8*)(&xtp[(g << 3) ^ cs]) = h;
  }
  __syncthreads();

  const int fr = lane & 15, fq = lane >> 4;
  bf16x8 af[2][2];                 // [m-tile][k-step]
  #pragma unroll
  for (int mt = 0; mt < 2; ++mt)
    #pragma unroll
    for (int ks = 0; ks < 2; ++ks){
      int m = mt * 16 + fr;
      int g = ks * 4 + fq;
      af[mt][ks] = __builtin_bit_cast(bf16x8,
          *(const u16x8*)&WL[m * 64 + ((g ^ (m & 7)) << 3)]);
    }
  const int colbase = w * 64;
  bf16x8 bfv[4][2];                // [c-tile][k-step]
  #pragma unroll
  for (int ct = 0; ct < 4; ++ct)
    #pragma unroll
    for (int ks = 0; ks < 2; ++ks){
      int c = colbase + ct * 16 + fr;
      int g = ks * 4 + fq;
      bfv[ct][ks] = __builtin_bit_cast(bf16x8,
          *(const u16x8*)&XT[c * 64 + ((g ^ (c & 7)) << 3)]);
    }
  f32x4 acc[2][4];
  #pragma unroll
  for (int mt = 0; mt < 2; ++mt)
    #pragma unroll
    for (int ct = 0; ct < 4; ++ct) acc[mt][ct] = (f32x4){0.f,0.f,0.f,0.f};
  #pragma unroll
  for (int mt = 0; mt < 2; ++mt)
    #pragma unroll
    for (int ct = 0; ct < 4; ++ct)
      #pragma unroll
      for (int ks = 0; ks < 2; ++ks)
        acc[mt][ct] = __builtin_amdgcn_mfma_f32_16x16x32_bf16(
            af[mt][ks], bfv[ct][ks], acc[mt][ct], 0, 0, 0);

  const u16* xr = xrad + (size_t)el * 4608;
  u16* o = msgS + (size_t)el * 7424;
  #pragma unroll
  for (int mt = 0; mt < 2; ++mt)
    #pragma unroll
    for (int ct = 0; ct < 4; ++ct){
      int col = colbase + ct * 16 + fr;
      #pragma unroll
      for (int r = 0; r < 4; ++r){
        int m = mt * 16 + fq * 4 + r;
        if (m < 29){
          int rr = (m < 13) ? m : (m < 24 ? m - 6 : m - 11);
          o[m * 256 + col] = f2bf(acc[mt][ct][r] * bf2f(xr[rr * 256 + col]));
        }
      }
    }
}

// ------------------------ gate + recombine (conv1) -------------------------
__global__ __launch_bounds__(128) void k_gate(
    const u16* __restrict__ c1m0, const u16* __restrict__ y10, const u16* __restrict__ y11,
    const u16* __restrict__ y20, const u16* __restrict__ y21, u16* __restrict__ msg2)
{
  int e = blockIdx.x, c = threadIdx.x;
  __shared__ float g[768];
  const u16* gp = c1m0 + (size_t)e * 1664;
  for (int i = c; i < 768; i += 128) g[i] = sigm(bf2f(gp[i]));
  __syncthreads();
  const u16* x0 = gp + 768;
  u16* o = msg2 + (size_t)e * 3712;
  { float v = bf2f(x0[c]); o[c] = f2bf(v * sigm(v)); }
  #pragma unroll
  for (int r = 1; r < 7; ++r)
    o[r * 128 + c] = f2bf(bf2f(x0[r * 128 + c]) * g[(r - 1) * 128 + c]);
  const u16* a0 = y10 + (size_t)e * 1536;
  const u16* a1 = y11 + (size_t)e * 1536;
  #pragma unroll
  for (int k = 0; k < 6; ++k){
    float orr = bf2f(a0[k * 128 + c]) - bf2f(a1[768 + k * 128 + c]);
    float oii = bf2f(a1[k * 128 + c]) + bf2f(a0[768 + k * 128 + c]);
    float gv = g[k * 128 + c];
    o[(7 + k)  * 128 + c] = f2bf(orr * gv);
    o[(13 + k) * 128 + c] = f2bf(oii * gv);
  }
  const u16* b0 = y20 + (size_t)e * 1280;
  const u16* b1 = y21 + (size_t)e * 1280;
  #pragma unroll
  for (int k = 0; k < 5; ++k){
    float orr = bf2f(b0[k * 128 + c]) - bf2f(b1[640 + k * 128 + c]);
    float oii = bf2f(b1[k * 128 + c]) + bf2f(b0[640 + k * 128 + c]);
    float gv = g[(1 + k) * 128 + c];
    o[(19 + k) * 128 + c] = f2bf(orr * gv);
    o[(24 + k) * 128 + c] = f2bf(oii * gv);
  }
}

// ------------- recombine2 + envelope -> TRANSPOSED msg3T (c,m) -------------
// msg3T[e][c][m], m-contiguous (32 per c, rows 29..31 zero) so wig_inv's
// B-operand is a k-contiguous b128 read.
__global__ __launch_bounds__(128) void k_recomb2(
    const u16* __restrict__ m3x0, const u16* __restrict__ z10, const u16* __restrict__ z11,
    const u16* __restrict__ z20, const u16* __restrict__ z21, const float* __restrict__ env,
    u16* __restrict__ msg3T)
{
  int e = blockIdx.x, c = threadIdx.x;
  float ev = env[e];
  u16 v[32];
  const u16* x0 = m3x0 + (size_t)e * 896;
  #pragma unroll
  for (int r = 0; r < 7; ++r) v[r] = f2bf(bf2f(x0[r * 128 + c]) * ev);
  const u16* a0 = z10 + (size_t)e * 1536;
  const u16* a1 = z11 + (size_t)e * 1536;
  #pragma unroll
  for (int k = 0; k < 6; ++k){
    float orr = bf2f(a0[k * 128 + c]) - bf2f(a1[768 + k * 128 + c]);
    float oii = bf2f(a1[k * 128 + c]) + bf2f(a0[768 + k * 128 + c]);
    v[7 + k]  = f2bf(orr * ev);
    v[13 + k] = f2bf(oii * ev);
  }
  const u16* b0 = z20 + (size_t)e * 1280;
  const u16* b1 = z21 + (size_t)e * 1280;
  #pragma unroll
  for (int k = 0; k < 5; ++k){
    float orr = bf2f(b0[k * 128 + c]) - bf2f(b1[640 + k * 128 + c]);
    float oii = bf2f(b1[k * 128 + c]) + bf2f(b0[640 + k * 128 + c]);
    v[19 + k] = f2bf(orr * ev);
    v[24 + k] = f2bf(oii * ev);
  }
  v[29] = 0; v[30] = 0; v[31] = 0;
  u16* o = msg3T + (size_t)e * 4096 + c * 32;
  #pragma unroll
  for (int q = 0; q < 4; ++q)
    *(u16x8*)(o + q * 8) = *(const u16x8*)(&v[q * 8]);
}

// -------------------- Wigner inverse (MFMA) + scatter-add ------------------
// out[dst][j][c] += sum_m Winv[j][m] msg3[m][c].  A = winv (LDS, padded
// 64x32, granule swizzle); B = msg3T read from global (coalesced b128).
__global__ __launch_bounds__(256) void k_wig_inv(
    const u16* __restrict__ msg3T, const float* __restrict__ winv,
    const int* __restrict__ eidx, float* __restrict__ out, int e0)
{
  __shared__ u16 WV[64 * 32];
  int el = blockIdx.x, tid = threadIdx.x;
  int eg = e0 + el;
  int lane = tid & 63, w = tid >> 6;
  const float* wp = winv + (size_t)eg * 1421;
  for (int idx = tid; idx < 2048; idx += 256){
    int j = idx >> 5, m = idx & 31;
    float v = (j < 49 && m < 29) ? wp[j * 29 + m] : 0.f;
    WV[j * 32 + (((m >> 3) ^ (j & 3)) << 3) + (m & 7)] = f2bf(v);
  }
  __syncthreads();

  const int fr = lane & 15, fq = lane >> 4;
  int jr = w * 16 + fr;
  bf16x8 a = __builtin_bit_cast(bf16x8,
      *(const u16x8*)&WV[jr * 32 + ((fq ^ (jr & 3)) << 3)]);
  const u16* bp = msg3T + (size_t)el * 4096;
  bf16x8 bfr[8];
  #pragma unroll
  for (int ct = 0; ct < 8; ++ct)
    bfr[ct] = __builtin_bit_cast(bf16x8,
        *(const u16x8*)(bp + (ct * 16 + fr) * 32 + fq * 8));
  f32x4 acc[8];
  #pragma unroll
  for (int ct = 0; ct < 8; ++ct){
    acc[ct] = (f32x4){0.f,0.f,0.f,0.f};
    acc[ct] = __builtin_amdgcn_mfma_f32_16x16x32_bf16(a, bfr[ct], acc[ct], 0, 0, 0);
  }
  int dst = eidx[E_NUM + eg];
  float* op = out + (size_t)dst * 6272;
  #pragma unroll
  for (int ct = 0; ct < 8; ++ct){
    int c = ct * 16 + fr;
    #pragma unroll
    for (int r = 0; r < 4; ++r){
      int j = w * 16 + fq * 4 + r;
      if (j < 49) atomicAdd(op + j * 128 + c, acc[ct][r]);
    }
  }
}

// ---------------------------------------------------------------------------
extern "C" void kernel_launch(void* const* d_in, const int* in_sizes, int n_in,
                              void* d_out, int out_size, void* d_ws, size_t ws_size,
                              hipStream_t stream)
{
  (void)in_sizes; (void)n_in;
  const float* x       = (const float*)d_in[0];
  const float* x_edge  = (const float*)d_in[1];
  const int*   eidx    = (const int*)d_in[3];
  const float* wig     = (const float*)d_in[4];
  const float* wig_inv = (const float*)d_in[5];
  const float* env     = (const float*)d_in[6];
  const float* rad_w0  = (const float*)d_in[7];
  const float* rad_b0  = (const float*)d_in[8];
  const float* ln0_s   = (const float*)d_in[9];
  const float* ln0_b   = (const float*)d_in[10];
  const float* rad_w1  = (const float*)d_in[11];
  const float* rad_b1  = (const float*)d_in[12];
  const float* ln1_s   = (const float*)d_in[13];
  const float* ln1_b   = (const float*)d_in[14];
  const float* rad_w2  = (const float*)d_in[15];
  const float* rad_b2  = (const float*)d_in[16];
  const float* c1w0    = (const float*)d_in[17];
  const float* c1b0    = (const float*)d_in[18];
  const float* c1w1    = (const float*)d_in[19];
  const float* c1w2    = (const float*)d_in[20];
  const float* c2w0    = (const float*)d_in[21];
  const float* c2b0    = (const float*)d_in[22];
  const float* c2w1    = (const float*)d_in[23];
  const float* c2w2    = (const float*)d_in[24];
  float* out = (float*)d_out;

  char* base = (char*)d_ws;
  size_t off = 0;
  auto alloc = [&](size_t bytes) -> char* {
    off = (off + 255) & ~(size_t)255;
    char* r = base + off;
    off += bytes;
    return r;
  };

  // ---- fixed area: transposed bf16 weights (~22.2 MB) ----
  u16* wtR0  = (u16*)alloc((size_t)256  * 128  * 2);
  u16* wtR1  = (u16*)alloc((size_t)256  * 256  * 2);
  u16* wtR2  = (u16*)alloc((size_t)4608 * 256  * 2);
  u16* wtC10 = (u16*)alloc((size_t)1664 * 1792 * 2);
  u16* wtC11 = (u16*)alloc((size_t)1536 * 1536 * 2);
  u16* wtC12 = (u16*)alloc((size_t)1280 * 1280 * 2);
  u16* wtC20 = (u16*)alloc((size_t)896  * 896  * 2);
  u16* wtC21 = (u16*)alloc((size_t)1536 * 768  * 2);
  u16* wtC22 = (u16*)alloc((size_t)1280 * 640  * 2);

  // ---- chunk size from remaining workspace (40,960 B per edge) ----
  size_t fixed_end = (off + 65536) & ~(size_t)65535;
  size_t avail = (ws_size > fixed_end + (1u << 20)) ? (ws_size - fixed_end - (1u << 20)) : 0;
  int CH = (int)(avail / 40960);
  if (CH > 5000) CH = 5000;
  CH &= ~63;
  if (CH < 64) CH = 64;

  off = fixed_end;
  const size_t C = (size_t)CH;
  u16*   xe   = (u16*)alloc(C * 128 * 2);
  float* tmp  = (float*)alloc(C * 256 * 4);
  u16*   h0   = (u16*)alloc(C * 256 * 2);
  u16*   h1   = (u16*)alloc(C * 256 * 2);
  u16* region1 = (u16*)alloc(C * 4608 * 2);   // xrad -> msg2
  u16* region2 = (u16*)alloc(C * 7424 * 2);   // msgS -> conv2 outs
  u16* region3 = (u16*)alloc(C * 7296 * 2);   // conv1 outs -> msg3T
  u16* xrad = region1;
  u16* msg2 = region1;
  u16* msgS = region2;
  u16* m3x0 = region2;                 // (C,896)
  u16* z10  = region2 + C * 896;       // (C,1536)
  u16* z11  = region2 + C * 2432;      // (C,1536)
  u16* z20  = region2 + C * 3968;      // (C,1280)
  u16* z21  = region2 + C * 5248;      // (C,1280)
  u16* c1m0b = region3;                // (C,1664)
  u16* y10   = region3 + C * 1664;     // (C,1536)
  u16* y11   = region3 + C * 3200;     // (C,1536)
  u16* y20   = region3 + C * 4736;     // (C,1280)
  u16* y21   = region3 + C * 6016;     // (C,1280)
  u16* msg3T = region3;                // (C,4096) transposed (c,m)

  hipMemsetAsync(d_out, 0, (size_t)out_size * sizeof(float), stream);

  auto tw = [&](const float* in, u16* o, int K, int N){
    k_transpose_w<<<dim3(N / 32, K / 32), 256, 0, stream>>>(in, o, K, N);
  };
  tw(rad_w0, wtR0, 128, 256);
  tw(rad_w1, wtR1, 256, 256);
  tw(rad_w2, wtR2, 256, 4608);
  tw(c1w0, wtC10, 1792, 1664);
  tw(c1w1, wtC11, 1536, 1536);
  tw(c1w2, wtC12, 1280, 1280);
  tw(c2w0, wtC20, 896, 896);
  tw(c2w1, wtC21, 768, 1536);
  tw(c2w2, wtC22, 640, 1280);

  auto gemm = [&](const u16* A, int lda, const u16* B, const float* bias,
                  float* Cf, u16* Cb, int ldc, int M, int N, int K){
    k_gemm_bt<<<dim3(N / 128, (M + 127) / 128), 256, 0, stream>>>(
        A, lda, B, bias, Cf, Cb, ldc, M, N, K);
  };

  for (int e0 = 0; e0 < E_NUM; e0 += CH){
    int cm = E_NUM - e0 < CH ? E_NUM - e0 : CH;

    k_f2bf<<<(cm * 128 + 255) / 256, 256, 0, stream>>>(x_edge + (size_t)e0 * 128, xe, cm * 128);

    // radial MLP
    gemm(xe, 128, wtR0, rad_b0, tmp, nullptr, 256, cm, 256, 128);
    k_ln_silu<<<cm, 256, 0, stream>>>(tmp, ln0_s, ln0_b, h0);
    gemm(h0, 256, wtR1, rad_b1, tmp, nullptr, 256, cm, 256, 256);
    k_ln_silu<<<cm, 256, 0, stream>>>(tmp, ln1_s, ln1_b, h1);
    gemm(h1, 256, wtR2, rad_b2, nullptr, xrad, 4608, cm, 4608, 256);

    // wigner forward + gather + radial scale (MFMA)
    k_wig_fwd<<<cm, 256, 0, stream>>>(x, eidx, wig, xrad, msgS, e0);

    // conv1
    gemm(msgS,        7424, wtC10, c1b0,    nullptr, c1m0b, 1664, cm, 1664, 1792);
    gemm(msgS + 1792, 7424, wtC11, nullptr, nullptr, y10,  1536, cm, 1536, 1536);
    gemm(msgS + 3328, 7424, wtC11, nullptr, nullptr, y11,  1536, cm, 1536, 1536);
    gemm(msgS + 4864, 7424, wtC12, nullptr, nullptr, y20,  1280, cm, 1280, 1280);
    gemm(msgS + 6144, 7424, wtC12, nullptr, nullptr, y21,  1280, cm, 1280, 1280);

    k_gate<<<cm, 128, 0, stream>>>(c1m0b, y10, y11, y20, y21, msg2);

    // conv2
    gemm(msg2,        3712, wtC20, c2b0,    nullptr, m3x0, 896,  cm, 896,  896);
    gemm(msg2 + 896,  3712, wtC21, nullptr, nullptr, z10, 1536, cm, 1536, 768);
    gemm(msg2 + 1664, 3712, wtC21, nullptr, nullptr, z11, 1536, cm, 1536, 768);
    gemm(msg2 + 2432, 3712, wtC22, nullptr, nullptr, z20, 1280, cm, 1280, 640);
    gemm(msg2 + 3072, 3712, wtC22, nullptr, nullptr, z21, 1280, cm, 1280, 640);

    k_recomb2<<<cm, 128, 0, stream>>>(m3x0, z10, z11, z20, z21, env + e0, msg3T);

    // wigner inverse + scatter (MFMA)
    k_wig_inv<<<cm, 256, 0, stream>>>(msg3T, wig_inv, eidx, out, e0);
  }
}

// Round 6
// 3231.128 us; speedup vs baseline: 1.2593x; 1.0389x over previous
//
#include <hip/hip_runtime.h>
#include <stdint.h>

// ---------------------------------------------------------------------------
// Edgewise (eSCN SO(2) conv block), MI355X gfx950.
// Round 6: dst-sorted edge permutation (counting sort on device) + run-gather
// wig_inv: one MFMA-chained accumulation per (node,chunk), ~4x fewer atomics,
// L2-clustered RMW. Chunk pipeline operates in permuted edge order.
// ---------------------------------------------------------------------------

#define E_NUM   20000
#define NN      5000

typedef uint16_t u16;
typedef __bf16  bf16x8 __attribute__((ext_vector_type(8)));
typedef float   f32x4  __attribute__((ext_vector_type(4)));
typedef uint16_t u16x8 __attribute__((ext_vector_type(8)));

__device__ __forceinline__ float bf2f(u16 h){
  uint32_t u = ((uint32_t)h) << 16;
  return __builtin_bit_cast(float, u);
}
__device__ __forceinline__ u16 f2bf(float f){
  uint32_t u = __builtin_bit_cast(uint32_t, f);
  u += 0x7fffu + ((u >> 16) & 1u);
  return (u16)(u >> 16);
}
__device__ __forceinline__ float sigm(float x){ return 1.f / (1.f + __expf(-x)); }

__device__ __forceinline__ void gload16(const void* g, void* l){
  __builtin_amdgcn_global_load_lds(
      (const __attribute__((address_space(1))) void*)g,
      (__attribute__((address_space(3))) void*)l, 16, 0, 0);
}

// ----------------------- dst counting sort ---------------------------------
__global__ void k_hist(const int* __restrict__ eidx, int* __restrict__ cnt){
  int e = blockIdx.x * 256 + threadIdx.x;
  if (e < E_NUM) atomicAdd(&cnt[eidx[E_NUM + e]], 1);
}
__global__ __launch_bounds__(256) void k_scan(const int* __restrict__ cnt,
                                              int* __restrict__ off){
  __shared__ int part[256];
  int t = threadIdx.x;
  int s = 0;
  #pragma unroll
  for (int i = 0; i < 20; ++i){
    int idx = t * 20 + i;
    if (idx < NN) s += cnt[idx];
  }
  part[t] = s;
  __syncthreads();
  if (t == 0){
    int run = 0;
    for (int i = 0; i < 256; ++i){ int v = part[i]; part[i] = run; run += v; }
  }
  __syncthreads();
  int run = part[t];
  #pragma unroll
  for (int i = 0; i < 20; ++i){
    int idx = t * 20 + i;
    if (idx < NN){ off[idx] = run; run += cnt[idx]; }
  }
}
__global__ void k_scatter(const int* __restrict__ eidx, int* __restrict__ off,
                          int* __restrict__ perm){
  int e = blockIdx.x * 256 + threadIdx.x;
  if (e < E_NUM){
    int pos = atomicAdd(&off[eidx[E_NUM + e]], 1);
    perm[pos] = e;
  }
}

// --------------------------- weight transpose ------------------------------
__global__ void k_transpose_w(const float* __restrict__ in, u16* __restrict__ out,
                              int K, int N){
  __shared__ float t[32][33];
  int nb = blockIdx.x * 32, kb = blockIdx.y * 32;
  int tx = threadIdx.x & 31, ty = threadIdx.x >> 5;   // 32x8
  for (int i = ty; i < 32; i += 8)
    t[i][tx] = in[(size_t)(kb + i) * N + (nb + tx)];
  __syncthreads();
  for (int i = ty; i < 32; i += 8)
    out[(size_t)(nb + i) * K + (kb + tx)] = f2bf(t[tx][i]);
}

// gather x_edge rows in permuted order -> bf16
__global__ void k_gather_xe(const float* __restrict__ x_edge,
                            const int* __restrict__ perm,
                            u16* __restrict__ xe, int e0){
  int el = blockIdx.x, c = threadIdx.x;
  int pe = perm[e0 + el];
  xe[(size_t)el * 128 + c] = f2bf(x_edge[(size_t)pe * 128 + c]);
}

// ------------------------------- GEMM --------------------------------------
// C(M,N) = A(M,K) @ B^T, B given (N,K) bf16, both k-contiguous. m97 structure.
__global__ __launch_bounds__(256) void k_gemm_bt(
    const u16* __restrict__ A, int lda,
    const u16* __restrict__ B,
    const float* __restrict__ bias,
    float* __restrict__ Cf, u16* __restrict__ Cb, int ldc,
    int M, int N, int K)
{
  __shared__ u16 As[128 * 32];
  __shared__ u16 Bs[128 * 32];
  const int tid  = threadIdx.x;
  const int lane = tid & 63;
  const int wave = tid >> 6;
  const int wm = wave >> 1, wn = wave & 1;
  const int fr = lane & 15, fq = lane >> 4;
  const int bn = blockIdx.x, bm = blockIdx.y;
  const int row0 = bm * 128;

  const int lr  = lane >> 2;
  const int lg  = lane & 3;
  const int rA0 = wave * 32 + lr;
  const int rA1 = rA0 + 16;
  const int g0  = lg ^ ((rA0 >> 1) & 3);
  const int g1  = lg ^ ((rA1 >> 1) & 3);
  int gra0 = row0 + rA0; if (gra0 > M - 1) gra0 = M - 1;
  int gra1 = row0 + rA1; if (gra1 > M - 1) gra1 = M - 1;
  const u16* aS0 = A + (size_t)gra0 * lda + g0 * 8;
  const u16* aS1 = A + (size_t)gra1 * lda + g1 * 8;
  const u16* bS0 = B + (size_t)(bn * 128 + rA0) * K + g0 * 8;
  const u16* bS1 = B + (size_t)(bn * 128 + rA1) * K + g1 * 8;
  u16* aD0 = As + (wave * 32) * 32;
  u16* aD1 = As + (wave * 32 + 16) * 32;
  u16* bD0 = Bs + (wave * 32) * 32;
  u16* bD1 = Bs + (wave * 32 + 16) * 32;

  const u16* afp[4]; const u16* bfp[4];
  #pragma unroll
  for (int mi = 0; mi < 4; ++mi){
    int r = wm * 64 + mi * 16 + fr;
    afp[mi] = As + r * 32 + (fq ^ ((r >> 1) & 3)) * 8;
  }
  #pragma unroll
  for (int ni = 0; ni < 4; ++ni){
    int r = wn * 64 + ni * 16 + fr;
    bfp[ni] = Bs + r * 32 + (fq ^ ((r >> 1) & 3)) * 8;
  }

  f32x4 acc[4][4];
  #pragma unroll
  for (int i = 0; i < 4; ++i)
    #pragma unroll
    for (int j = 0; j < 4; ++j) acc[i][j] = (f32x4){0.f, 0.f, 0.f, 0.f};

  for (int k0 = 0; k0 < K; k0 += 32){
    gload16(aS0 + k0, aD0);
    gload16(aS1 + k0, aD1);
    gload16(bS0 + k0, bD0);
    gload16(bS1 + k0, bD1);
    __syncthreads();
    bf16x8 af[4], bfv[4];
    #pragma unroll
    for (int mi = 0; mi < 4; ++mi)
      af[mi] = __builtin_bit_cast(bf16x8, *(const u16x8*)afp[mi]);
    #pragma unroll
    for (int ni = 0; ni < 4; ++ni)
      bfv[ni] = __builtin_bit_cast(bf16x8, *(const u16x8*)bfp[ni]);
    #pragma unroll
    for (int mi = 0; mi < 4; ++mi)
      #pragma unroll
      for (int ni = 0; ni < 4; ++ni)
        acc[mi][ni] = __builtin_amdgcn_mfma_f32_16x16x32_bf16(af[mi], bfv[ni], acc[mi][ni], 0, 0, 0);
    __syncthreads();
  }

  #pragma unroll
  for (int ni = 0; ni < 4; ++ni){
    int col = bn * 128 + wn * 64 + ni * 16 + fr;
    float bv = bias ? bias[col] : 0.f;
    #pragma unroll
    for (int mi = 0; mi < 4; ++mi){
      #pragma unroll
      for (int i = 0; i < 4; ++i){
        int row = row0 + wm * 64 + mi * 16 + fq * 4 + i;
        if (row < M){
          float v = acc[mi][ni][i] + bv;
          if (Cb) Cb[(size_t)row * ldc + col] = f2bf(v);
          else    Cf[(size_t)row * ldc + col] = v;
        }
      }
    }
  }
}

// --------------------------- LayerNorm + SiLU ------------------------------
__global__ __launch_bounds__(256) void k_ln_silu(
    const float* __restrict__ in, const float* __restrict__ sc,
    const float* __restrict__ bb, u16* __restrict__ out)
{
  int e = blockIdx.x, t = threadIdx.x;
  float v = in[(size_t)e * 256 + t];
  float s1 = v, s2 = v * v;
  #pragma unroll
  for (int off = 32; off > 0; off >>= 1){
    s1 += __shfl_down(s1, off);
    s2 += __shfl_down(s2, off);
  }
  __shared__ float r1[4], r2[4];
  if ((t & 63) == 0){ r1[t >> 6] = s1; r2[t >> 6] = s2; }
  __syncthreads();
  float S1 = r1[0] + r1[1] + r1[2] + r1[3];
  float S2 = r2[0] + r2[1] + r2[2] + r2[3];
  float mu  = S1 * (1.f / 256.f);
  float var = S2 * (1.f / 256.f) - mu * mu;
  float nv = (v - mu) * rsqrtf(var + 1e-5f) * sc[t] + bb[t];
  out[(size_t)e * 256 + t] = f2bf(nv * sigm(nv));
}

// --------------------- Wigner forward (MFMA, permuted) ---------------------
__global__ __launch_bounds__(256) void k_wig_fwd(
    const float* __restrict__ x, const int* __restrict__ eidx,
    const float* __restrict__ wig, const u16* __restrict__ xrad,
    u16* __restrict__ msgS, const int* __restrict__ perm, int e0)
{
  __shared__ u16 XT[256 * 64];
  __shared__ u16 WL[32 * 64];
  int el = blockIdx.x, tid = threadIdx.x;
  int eg = perm[e0 + el];
  int lane = tid & 63, w = tid >> 6;

  const float* wp = wig + (size_t)eg * 1421;
  for (int idx = tid; idx < 2048; idx += 256){
    int m = idx >> 6, k = idx & 63;
    float v = (m < 29 && k < 49) ? wp[m * 49 + k] : 0.f;
    WL[m * 64 + ((((k >> 3) ^ (m & 7))) << 3) + (k & 7)] = f2bf(v);
  }

  int node = eidx[((w >> 1) ? E_NUM : 0) + eg];
  const float* xp = x + (size_t)node * 6272 + ((w & 1) * 64 + lane);
  int xtc = w * 64 + lane;
  u16* xtp = &XT[xtc * 64];
  const int cs = (xtc & 7) << 3;
  #pragma unroll
  for (int g = 0; g < 8; ++g){
    u16x8 h = {0,0,0,0,0,0,0,0};
    #pragma unroll
    for (int i = 0; i < 8; ++i){
      int k = g * 8 + i;
      if (k < 49) h[i] = f2bf(xp[k * 128]);
    }
    *(u16x8*)(&xtp[(g << 3) ^ cs]) = h;
  }
  __syncthreads();

  const int fr = lane & 15, fq = lane >> 4;
  bf16x8 af[2][2];
  #pragma unroll
  for (int mt = 0; mt < 2; ++mt)
    #pragma unroll
    for (int ks = 0; ks < 2; ++ks){
      int m = mt * 16 + fr;
      int g = ks * 4 + fq;
      af[mt][ks] = __builtin_bit_cast(bf16x8,
          *(const u16x8*)&WL[m * 64 + ((g ^ (m & 7)) << 3)]);
    }
  const int colbase = w * 64;
  bf16x8 bfv[4][2];
  #pragma unroll
  for (int ct = 0; ct < 4; ++ct)
    #pragma unroll
    for (int ks = 0; ks < 2; ++ks){
      int c = colbase + ct * 16 + fr;
      int g = ks * 4 + fq;
      bfv[ct][ks] = __builtin_bit_cast(bf16x8,
          *(const u16x8*)&XT[c * 64 + ((g ^ (c & 7)) << 3)]);
    }
  f32x4 acc[2][4];
  #pragma unroll
  for (int mt = 0; mt < 2; ++mt)
    #pragma unroll
    for (int ct = 0; ct < 4; ++ct) acc[mt][ct] = (f32x4){0.f,0.f,0.f,0.f};
  #pragma unroll
  for (int mt = 0; mt < 2; ++mt)
    #pragma unroll
    for (int ct = 0; ct < 4; ++ct)
      #pragma unroll
      for (int ks = 0; ks < 2; ++ks)
        acc[mt][ct] = __builtin_amdgcn_mfma_f32_16x16x32_bf16(
            af[mt][ks], bfv[ct][ks], acc[mt][ct], 0, 0, 0);

  const u16* xr = xrad + (size_t)el * 4608;
  u16* o = msgS + (size_t)el * 7424;
  #pragma unroll
  for (int mt = 0; mt < 2; ++mt)
    #pragma unroll
    for (int ct = 0; ct < 4; ++ct){
      int col = colbase + ct * 16 + fr;
      #pragma unroll
      for (int r = 0; r < 4; ++r){
        int m = mt * 16 + fq * 4 + r;
        if (m < 29){
          int rr = (m < 13) ? m : (m < 24 ? m - 6 : m - 11);
          o[m * 256 + col] = f2bf(acc[mt][ct][r] * bf2f(xr[rr * 256 + col]));
        }
      }
    }
}

// ------------------------ gate + recombine (conv1) -------------------------
__global__ __launch_bounds__(128) void k_gate(
    const u16* __restrict__ c1m0, const u16* __restrict__ y10, const u16* __restrict__ y11,
    const u16* __restrict__ y20, const u16* __restrict__ y21, u16* __restrict__ msg2)
{
  int e = blockIdx.x, c = threadIdx.x;
  __shared__ float g[768];
  const u16* gp = c1m0 + (size_t)e * 1664;
  for (int i = c; i < 768; i += 128) g[i] = sigm(bf2f(gp[i]));
  __syncthreads();
  const u16* x0 = gp + 768;
  u16* o = msg2 + (size_t)e * 3712;
  { float v = bf2f(x0[c]); o[c] = f2bf(v * sigm(v)); }
  #pragma unroll
  for (int r = 1; r < 7; ++r)
    o[r * 128 + c] = f2bf(bf2f(x0[r * 128 + c]) * g[(r - 1) * 128 + c]);
  const u16* a0 = y10 + (size_t)e * 1536;
  const u16* a1 = y11 + (size_t)e * 1536;
  #pragma unroll
  for (int k = 0; k < 6; ++k){
    float orr = bf2f(a0[k * 128 + c]) - bf2f(a1[768 + k * 128 + c]);
    float oii = bf2f(a1[k * 128 + c]) + bf2f(a0[768 + k * 128 + c]);
    float gv = g[k * 128 + c];
    o[(7 + k)  * 128 + c] = f2bf(orr * gv);
    o[(13 + k) * 128 + c] = f2bf(oii * gv);
  }
  const u16* b0 = y20 + (size_t)e * 1280;
  const u16* b1 = y21 + (size_t)e * 1280;
  #pragma unroll
  for (int k = 0; k < 5; ++k){
    float orr = bf2f(b0[k * 128 + c]) - bf2f(b1[640 + k * 128 + c]);
    float oii = bf2f(b1[k * 128 + c]) + bf2f(b0[640 + k * 128 + c]);
    float gv = g[(1 + k) * 128 + c];
    o[(19 + k) * 128 + c] = f2bf(orr * gv);
    o[(24 + k) * 128 + c] = f2bf(oii * gv);
  }
}

// ------------- recombine2 + envelope -> TRANSPOSED msg3T (c,m) -------------
__global__ __launch_bounds__(128) void k_recomb2(
    const u16* __restrict__ m3x0, const u16* __restrict__ z10, const u16* __restrict__ z11,
    const u16* __restrict__ z20, const u16* __restrict__ z21, const float* __restrict__ env,
    u16* __restrict__ msg3T, const int* __restrict__ perm, int e0)
{
  int e = blockIdx.x, c = threadIdx.x;
  float ev = env[perm[e0 + e]];
  u16 v[32];
  const u16* x0 = m3x0 + (size_t)e * 896;
  #pragma unroll
  for (int r = 0; r < 7; ++r) v[r] = f2bf(bf2f(x0[r * 128 + c]) * ev);
  const u16* a0 = z10 + (size_t)e * 1536;
  const u16* a1 = z11 + (size_t)e * 1536;
  #pragma unroll
  for (int k = 0; k < 6; ++k){
    float orr = bf2f(a0[k * 128 + c]) - bf2f(a1[768 + k * 128 + c]);
    float oii = bf2f(a1[k * 128 + c]) + bf2f(a0[768 + k * 128 + c]);
    v[7 + k]  = f2bf(orr * ev);
    v[13 + k] = f2bf(oii * ev);
  }
  const u16* b0 = z20 + (size_t)e * 1280;
  const u16* b1 = z21 + (size_t)e * 1280;
  #pragma unroll
  for (int k = 0; k < 5; ++k){
    float orr = bf2f(b0[k * 128 + c]) - bf2f(b1[640 + k * 128 + c]);
    float oii = bf2f(b1[k * 128 + c]) + bf2f(b0[640 + k * 128 + c]);
    v[19 + k] = f2bf(orr * ev);
    v[24 + k] = f2bf(oii * ev);
  }
  v[29] = 0; v[30] = 0; v[31] = 0;
  u16* o = msg3T + (size_t)e * 4096 + c * 32;
  #pragma unroll
  for (int q = 0; q < 4; ++q)
    *(u16x8*)(o + q * 8) = *(const u16x8*)(&v[q * 8]);
}

// ------------- Wigner inverse (MFMA, run-gather) + scatter-add -------------
// Edges sorted by dst: block at run start walks all same-dst edges in chunk,
// chaining MFMA accumulation; one atomic set per (node,chunk).
__global__ __launch_bounds__(256) void k_wig_inv(
    const u16* __restrict__ msg3T, const float* __restrict__ winv,
    const int* __restrict__ eidx, float* __restrict__ out,
    const int* __restrict__ perm, int e0, int cm)
{
  __shared__ u16 WV[64 * 32];
  int el = blockIdx.x, tid = threadIdx.x;
  int i = e0 + el;
  int d = eidx[E_NUM + perm[i]];
  if (el > 0 && eidx[E_NUM + perm[i - 1]] == d) return;   // not a run start
  int lane = tid & 63, w = tid >> 6;
  const int fr = lane & 15, fq = lane >> 4;
  const int jr = w * 16 + fr;

  f32x4 acc[8];
  #pragma unroll
  for (int ct = 0; ct < 8; ++ct) acc[ct] = (f32x4){0.f,0.f,0.f,0.f};

  int tend = e0 + cm;
  for (int t = i; t < tend; ++t){
    int pe = perm[t];
    if (t > i && eidx[E_NUM + pe] != d) break;
    __syncthreads();                       // prev iter's reads done
    const float* wp = winv + (size_t)pe * 1421;
    for (int idx = tid; idx < 2048; idx += 256){
      int j = idx >> 5, m = idx & 31;
      float v = (j < 49 && m < 29) ? wp[j * 29 + m] : 0.f;
      WV[j * 32 + (((m >> 3) ^ (j & 3)) << 3) + (m & 7)] = f2bf(v);
    }
    __syncthreads();
    bf16x8 a = __builtin_bit_cast(bf16x8,
        *(const u16x8*)&WV[jr * 32 + ((fq ^ (jr & 3)) << 3)]);
    const u16* bp = msg3T + (size_t)(t - e0) * 4096;
    #pragma unroll
    for (int ct = 0; ct < 8; ++ct){
      bf16x8 b = __builtin_bit_cast(bf16x8,
          *(const u16x8*)(bp + (ct * 16 + fr) * 32 + fq * 8));
      acc[ct] = __builtin_amdgcn_mfma_f32_16x16x32_bf16(a, b, acc[ct], 0, 0, 0);
    }
  }

  float* op = out + (size_t)d * 6272;
  #pragma unroll
  for (int ct = 0; ct < 8; ++ct){
    int c = ct * 16 + fr;
    #pragma unroll
    for (int r = 0; r < 4; ++r){
      int j = w * 16 + fq * 4 + r;
      if (j < 49) atomicAdd(op + j * 128 + c, acc[ct][r]);
    }
  }
}

// ---------------------------------------------------------------------------
extern "C" void kernel_launch(void* const* d_in, const int* in_sizes, int n_in,
                              void* d_out, int out_size, void* d_ws, size_t ws_size,
                              hipStream_t stream)
{
  (void)in_sizes; (void)n_in;
  const float* x       = (const float*)d_in[0];
  const float* x_edge  = (const float*)d_in[1];
  const int*   eidx    = (const int*)d_in[3];
  const float* wig     = (const float*)d_in[4];
  const float* wig_inv = (const float*)d_in[5];
  const float* env     = (const float*)d_in[6];
  const float* rad_w0  = (const float*)d_in[7];
  const float* rad_b0  = (const float*)d_in[8];
  const float* ln0_s   = (const float*)d_in[9];
  const float* ln0_b   = (const float*)d_in[10];
  const float* rad_w1  = (const float*)d_in[11];
  const float* rad_b1  = (const float*)d_in[12];
  const float* ln1_s   = (const float*)d_in[13];
  const float* ln1_b   = (const float*)d_in[14];
  const float* rad_w2  = (const float*)d_in[15];
  const float* rad_b2  = (const float*)d_in[16];
  const float* c1w0    = (const float*)d_in[17];
  const float* c1b0    = (const float*)d_in[18];
  const float* c1w1    = (const float*)d_in[19];
  const float* c1w2    = (const float*)d_in[20];
  const float* c2w0    = (const float*)d_in[21];
  const float* c2b0    = (const float*)d_in[22];
  const float* c2w1    = (const float*)d_in[23];
  const float* c2w2    = (const float*)d_in[24];
  float* out = (float*)d_out;

  char* base = (char*)d_ws;
  size_t off = 0;
  auto alloc = [&](size_t bytes) -> char* {
    off = (off + 255) & ~(size_t)255;
    char* r = base + off;
    off += bytes;
    return r;
  };

  // ---- fixed area: transposed bf16 weights (~22.2 MB) + sort arrays ----
  u16* wtR0  = (u16*)alloc((size_t)256  * 128  * 2);
  u16* wtR1  = (u16*)alloc((size_t)256  * 256  * 2);
  u16* wtR2  = (u16*)alloc((size_t)4608 * 256  * 2);
  u16* wtC10 = (u16*)alloc((size_t)1664 * 1792 * 2);
  u16* wtC11 = (u16*)alloc((size_t)1536 * 1536 * 2);
  u16* wtC12 = (u16*)alloc((size_t)1280 * 1280 * 2);
  u16* wtC20 = (u16*)alloc((size_t)896  * 896  * 2);
  u16* wtC21 = (u16*)alloc((size_t)1536 * 768  * 2);
  u16* wtC22 = (u16*)alloc((size_t)1280 * 640  * 2);
  int* cnt   = (int*)alloc(NN * 4);
  int* soff  = (int*)alloc(NN * 4);
  int* perm  = (int*)alloc(E_NUM * 4);

  // ---- chunk size from remaining workspace (40,960 B per edge) ----
  size_t fixed_end = (off + 65536) & ~(size_t)65535;
  size_t avail = (ws_size > fixed_end + (1u << 20)) ? (ws_size - fixed_end - (1u << 20)) : 0;
  int CH = (int)(avail / 40960);
  if (CH > 5000) CH = 5000;
  CH &= ~63;
  if (CH < 64) CH = 64;

  off = fixed_end;
  const size_t C = (size_t)CH;
  u16*   xe   = (u16*)alloc(C * 128 * 2);
  float* tmp  = (float*)alloc(C * 256 * 4);
  u16*   h0   = (u16*)alloc(C * 256 * 2);
  u16*   h1   = (u16*)alloc(C * 256 * 2);
  u16* region1 = (u16*)alloc(C * 4608 * 2);   // xrad -> msg2
  u16* region2 = (u16*)alloc(C * 7424 * 2);   // msgS -> conv2 outs
  u16* region3 = (u16*)alloc(C * 7296 * 2);   // conv1 outs -> msg3T
  u16* xrad = region1;
  u16* msg2 = region1;
  u16* msgS = region2;
  u16* m3x0 = region2;                 // (C,896)
  u16* z10  = region2 + C * 896;       // (C,1536)
  u16* z11  = region2 + C * 2432;      // (C,1536)
  u16* z20  = region2 + C * 3968;      // (C,1280)
  u16* z21  = region2 + C * 5248;      // (C,1280)
  u16* c1m0b = region3;                // (C,1664)
  u16* y10   = region3 + C * 1664;     // (C,1536)
  u16* y11   = region3 + C * 3200;     // (C,1536)
  u16* y20   = region3 + C * 4736;     // (C,1280)
  u16* y21   = region3 + C * 6016;     // (C,1280)
  u16* msg3T = region3;                // (C,4096) transposed (c,m)

  hipMemsetAsync(d_out, 0, (size_t)out_size * sizeof(float), stream);
  hipMemsetAsync(cnt, 0, NN * 4, stream);

  // dst counting sort -> perm
  k_hist<<<(E_NUM + 255) / 256, 256, 0, stream>>>(eidx, cnt);
  k_scan<<<1, 256, 0, stream>>>(cnt, soff);
  k_scatter<<<(E_NUM + 255) / 256, 256, 0, stream>>>(eidx, soff, perm);

  auto tw = [&](const float* in, u16* o, int K, int N){
    k_transpose_w<<<dim3(N / 32, K / 32), 256, 0, stream>>>(in, o, K, N);
  };
  tw(rad_w0, wtR0, 128, 256);
  tw(rad_w1, wtR1, 256, 256);
  tw(rad_w2, wtR2, 256, 4608);
  tw(c1w0, wtC10, 1792, 1664);
  tw(c1w1, wtC11, 1536, 1536);
  tw(c1w2, wtC12, 1280, 1280);
  tw(c2w0, wtC20, 896, 896);
  tw(c2w1, wtC21, 768, 1536);
  tw(c2w2, wtC22, 640, 1280);

  auto gemm = [&](const u16* A, int lda, const u16* B, const float* bias,
                  float* Cf, u16* Cb, int ldc, int M, int N, int K){
    k_gemm_bt<<<dim3(N / 128, (M + 127) / 128), 256, 0, stream>>>(
        A, lda, B, bias, Cf, Cb, ldc, M, N, K);
  };

  for (int e0 = 0; e0 < E_NUM; e0 += CH){
    int cm = E_NUM - e0 < CH ? E_NUM - e0 : CH;

    k_gather_xe<<<cm, 128, 0, stream>>>(x_edge, perm, xe, e0);

    // radial MLP
    gemm(xe, 128, wtR0, rad_b0, tmp, nullptr, 256, cm, 256, 128);
    k_ln_silu<<<cm, 256, 0, stream>>>(tmp, ln0_s, ln0_b, h0);
    gemm(h0, 256, wtR1, rad_b1, tmp, nullptr, 256, cm, 256, 256);
    k_ln_silu<<<cm, 256, 0, stream>>>(tmp, ln1_s, ln1_b, h1);
    gemm(h1, 256, wtR2, rad_b2, nullptr, xrad, 4608, cm, 4608, 256);

    // wigner forward + gather + radial scale (MFMA, permuted)
    k_wig_fwd<<<cm, 256, 0, stream>>>(x, eidx, wig, xrad, msgS, perm, e0);

    // conv1
    gemm(msgS,        7424, wtC10, c1b0,    nullptr, c1m0b, 1664, cm, 1664, 1792);
    gemm(msgS + 1792, 7424, wtC11, nullptr, nullptr, y10,  1536, cm, 1536, 1536);
    gemm(msgS + 3328, 7424, wtC11, nullptr, nullptr, y11,  1536, cm, 1536, 1536);
    gemm(msgS + 4864, 7424, wtC12, nullptr, nullptr, y20,  1280, cm, 1280, 1280);
    gemm(msgS + 6144, 7424, wtC12, nullptr, nullptr, y21,  1280, cm, 1280, 1280);

    k_gate<<<cm, 128, 0, stream>>>(c1m0b, y10, y11, y20, y21, msg2);

    // conv2
    gemm(msg2,        3712, wtC20, c2b0,    nullptr, m3x0, 896,  cm, 896,  896);
    gemm(msg2 + 896,  3712, wtC21, nullptr, nullptr, z10, 1536, cm, 1536, 768);
    gemm(msg2 + 1664, 3712, wtC21, nullptr, nullptr, z11, 1536, cm, 1536, 768);
    gemm(msg2 + 2432, 3712, wtC22, nullptr, nullptr, z20, 1280, cm, 1280, 640);
    gemm(msg2 + 3072, 3712, wtC22, nullptr, nullptr, z21, 1280, cm, 1280, 640);

    k_recomb2<<<cm, 128, 0, stream>>>(m3x0, z10, z11, z20, z21, env, msg3T, perm, e0);

    // wigner inverse + run-gather scatter (MFMA)
    k_wig_inv<<<cm, 256, 0, stream>>>(msg3T, wig_inv, eidx, out, perm, e0, cm);
  }
}

// Round 8
// 2521.425 us; speedup vs baseline: 1.6138x; 1.2815x over previous
//
#include <hip/hip_runtime.h>
#include <stdint.h>

// ---------------------------------------------------------------------------
// Edgewise (eSCN SO(2) conv block), MI355X gfx950.
// Round 8: round-7 structure with the wig_fwd dst-half indexing fix
// (within-node column = c & 127). GEMM double-buffered, weight-shared GEMM
// pairs fused, x pre-transposed to bf16 xT, dst-sorted run-gather wig_inv.
// ---------------------------------------------------------------------------

#define E_NUM   20000
#define NN      5000

typedef uint16_t u16;
typedef __bf16  bf16x8 __attribute__((ext_vector_type(8)));
typedef float   f32x4  __attribute__((ext_vector_type(4)));
typedef uint16_t u16x8 __attribute__((ext_vector_type(8)));

__device__ __forceinline__ float bf2f(u16 h){
  uint32_t u = ((uint32_t)h) << 16;
  return __builtin_bit_cast(float, u);
}
__device__ __forceinline__ u16 f2bf(float f){
  uint32_t u = __builtin_bit_cast(uint32_t, f);
  u += 0x7fffu + ((u >> 16) & 1u);
  return (u16)(u >> 16);
}
__device__ __forceinline__ float sigm(float x){ return 1.f / (1.f + __expf(-x)); }

__device__ __forceinline__ void gload16(const void* g, void* l){
  __builtin_amdgcn_global_load_lds(
      (const __attribute__((address_space(1))) void*)g,
      (__attribute__((address_space(3))) void*)l, 16, 0, 0);
}

// ----------------------- dst counting sort ---------------------------------
__global__ void k_hist(const int* __restrict__ eidx, int* __restrict__ cnt){
  int e = blockIdx.x * 256 + threadIdx.x;
  if (e < E_NUM) atomicAdd(&cnt[eidx[E_NUM + e]], 1);
}
__global__ __launch_bounds__(256) void k_scan(const int* __restrict__ cnt,
                                              int* __restrict__ off){
  __shared__ int part[256];
  int t = threadIdx.x;
  int s = 0;
  #pragma unroll
  for (int i = 0; i < 20; ++i){
    int idx = t * 20 + i;
    if (idx < NN) s += cnt[idx];
  }
  part[t] = s;
  __syncthreads();
  if (t == 0){
    int run = 0;
    for (int i = 0; i < 256; ++i){ int v = part[i]; part[i] = run; run += v; }
  }
  __syncthreads();
  int run = part[t];
  #pragma unroll
  for (int i = 0; i < 20; ++i){
    int idx = t * 20 + i;
    if (idx < NN){ off[idx] = run; run += cnt[idx]; }
  }
}
__global__ void k_scatter(const int* __restrict__ eidx, int* __restrict__ off,
                          int* __restrict__ perm){
  int e = blockIdx.x * 256 + threadIdx.x;
  if (e < E_NUM){
    int pos = atomicAdd(&off[eidx[E_NUM + e]], 1);
    perm[pos] = e;
  }
}

// --------------------------- weight transpose ------------------------------
__global__ void k_transpose_w(const float* __restrict__ in, u16* __restrict__ out,
                              int K, int N){
  __shared__ float t[32][33];
  int nb = blockIdx.x * 32, kb = blockIdx.y * 32;
  int tx = threadIdx.x & 31, ty = threadIdx.x >> 5;   // 32x8
  for (int i = ty; i < 32; i += 8)
    t[i][tx] = in[(size_t)(kb + i) * N + (nb + tx)];
  __syncthreads();
  for (int i = ty; i < 32; i += 8)
    out[(size_t)(nb + i) * K + (kb + tx)] = f2bf(t[tx][i]);
}

// ------------- x -> xT bf16, [node][c=128][k=64 padded], once --------------
__global__ __launch_bounds__(256) void k_xpose(const float* __restrict__ x,
                                               u16* __restrict__ xT){
  __shared__ float t[6272];
  int n = blockIdx.x, tid = threadIdx.x;
  const float* xp = x + (size_t)n * 6272;
  for (int i = tid; i < 6272; i += 256) t[i] = xp[i];
  __syncthreads();
  int c = tid >> 1;
  int kh = (tid & 1) * 32;
  u16* o = xT + (size_t)n * 8192 + c * 64 + kh;
  #pragma unroll
  for (int q = 0; q < 4; ++q){
    u16x8 h;
    #pragma unroll
    for (int i = 0; i < 8; ++i){
      int k = kh + q * 8 + i;
      h[i] = (k < 49) ? f2bf(t[k * 128 + c]) : (u16)0;
    }
    *(u16x8*)(o + q * 8) = h;
  }
}

// gather x_edge rows in permuted order -> bf16
__global__ void k_gather_xe(const float* __restrict__ x_edge,
                            const int* __restrict__ perm,
                            u16* __restrict__ xe, int e0){
  int el = blockIdx.x, c = threadIdx.x;
  int pe = perm[e0 + el];
  xe[(size_t)el * 128 + c] = f2bf(x_edge[(size_t)pe * 128 + c]);
}

// ------------------------------- GEMM --------------------------------------
// C(M,N) = A(M,K) @ B^T, B given (N,K) bf16, both k-contiguous.
// Double-buffered LDS: stage(next) issued before compute(cur), ONE
// __syncthreads (vmcnt0+barrier) per K-step. Optional paired second A:
// blocks with blockIdx.y >= myb compute A2 -> Cb2 (same B).
__global__ __launch_bounds__(256) void k_gemm_bt(
    const u16* __restrict__ A, const u16* __restrict__ A2, int lda,
    const u16* __restrict__ B,
    const float* __restrict__ bias,
    float* __restrict__ Cf, u16* __restrict__ Cb, u16* __restrict__ Cb2,
    int ldc, int M, int N, int K, int myb)
{
  __shared__ u16 As[2][4096];
  __shared__ u16 Bs[2][4096];
  const int tid  = threadIdx.x;
  const int lane = tid & 63;
  const int wave = tid >> 6;
  const int wm = wave >> 1, wn = wave & 1;
  const int fr = lane & 15, fq = lane >> 4;
  const int bn = blockIdx.x;
  int bm = blockIdx.y;
  if (bm >= myb){ bm -= myb; A = A2; Cb = Cb2; }
  const int row0 = bm * 128;

  const int lr  = lane >> 2;
  const int lg  = lane & 3;
  const int rA0 = wave * 32 + lr;
  const int rA1 = rA0 + 16;
  const int g0  = lg ^ ((rA0 >> 1) & 3);
  const int g1  = lg ^ ((rA1 >> 1) & 3);
  int gra0 = row0 + rA0; if (gra0 > M - 1) gra0 = M - 1;
  int gra1 = row0 + rA1; if (gra1 > M - 1) gra1 = M - 1;
  const u16* aS0 = A + (size_t)gra0 * lda + g0 * 8;
  const u16* aS1 = A + (size_t)gra1 * lda + g1 * 8;
  const u16* bS0 = B + (size_t)(bn * 128 + rA0) * K + g0 * 8;
  const u16* bS1 = B + (size_t)(bn * 128 + rA1) * K + g1 * 8;
  const int dA0 = (wave * 32) * 32;
  const int dA1 = (wave * 32 + 16) * 32;

  int aoff[4], boff[4];
  #pragma unroll
  for (int mi = 0; mi < 4; ++mi){
    int r = wm * 64 + mi * 16 + fr;
    aoff[mi] = r * 32 + (fq ^ ((r >> 1) & 3)) * 8;
  }
  #pragma unroll
  for (int ni = 0; ni < 4; ++ni){
    int r = wn * 64 + ni * 16 + fr;
    boff[ni] = r * 32 + (fq ^ ((r >> 1) & 3)) * 8;
  }

  f32x4 acc[4][4];
  #pragma unroll
  for (int i = 0; i < 4; ++i)
    #pragma unroll
    for (int j = 0; j < 4; ++j) acc[i][j] = (f32x4){0.f, 0.f, 0.f, 0.f};

  auto stage = [&](int buf, int k0){
    gload16(aS0 + k0, &As[buf][dA0]);
    gload16(aS1 + k0, &As[buf][dA1]);
    gload16(bS0 + k0, &Bs[buf][dA0]);
    gload16(bS1 + k0, &Bs[buf][dA1]);
  };

  stage(0, 0);
  __syncthreads();
  int cur = 0;
  for (int k0 = 0; k0 < K; k0 += 32){
    if (k0 + 32 < K) stage(cur ^ 1, k0 + 32);
    bf16x8 af[4], bfv[4];
    #pragma unroll
    for (int mi = 0; mi < 4; ++mi)
      af[mi] = __builtin_bit_cast(bf16x8, *(const u16x8*)&As[cur][aoff[mi]]);
    #pragma unroll
    for (int ni = 0; ni < 4; ++ni)
      bfv[ni] = __builtin_bit_cast(bf16x8, *(const u16x8*)&Bs[cur][boff[ni]]);
    #pragma unroll
    for (int mi = 0; mi < 4; ++mi)
      #pragma unroll
      for (int ni = 0; ni < 4; ++ni)
        acc[mi][ni] = __builtin_amdgcn_mfma_f32_16x16x32_bf16(af[mi], bfv[ni], acc[mi][ni], 0, 0, 0);
    __syncthreads();          // drains vmcnt(0): next buffer landed
    cur ^= 1;
  }

  #pragma unroll
  for (int ni = 0; ni < 4; ++ni){
    int col = bn * 128 + wn * 64 + ni * 16 + fr;
    float bv = bias ? bias[col] : 0.f;
    #pragma unroll
    for (int mi = 0; mi < 4; ++mi){
      #pragma unroll
      for (int i = 0; i < 4; ++i){
        int row = row0 + wm * 64 + mi * 16 + fq * 4 + i;
        if (row < M){
          float v = acc[mi][ni][i] + bv;
          if (Cb) Cb[(size_t)row * ldc + col] = f2bf(v);
          else    Cf[(size_t)row * ldc + col] = v;
        }
      }
    }
  }
}

// --------------------------- LayerNorm + SiLU ------------------------------
__global__ __launch_bounds__(256) void k_ln_silu(
    const float* __restrict__ in, const float* __restrict__ sc,
    const float* __restrict__ bb, u16* __restrict__ out)
{
  int e = blockIdx.x, t = threadIdx.x;
  float v = in[(size_t)e * 256 + t];
  float s1 = v, s2 = v * v;
  #pragma unroll
  for (int off = 32; off > 0; off >>= 1){
    s1 += __shfl_down(s1, off);
    s2 += __shfl_down(s2, off);
  }
  __shared__ float r1[4], r2[4];
  if ((t & 63) == 0){ r1[t >> 6] = s1; r2[t >> 6] = s2; }
  __syncthreads();
  float S1 = r1[0] + r1[1] + r1[2] + r1[3];
  float S2 = r2[0] + r2[1] + r2[2] + r2[3];
  float mu  = S1 * (1.f / 256.f);
  float var = S2 * (1.f / 256.f) - mu * mu;
  float nv = (v - mu) * rsqrtf(var + 1e-5f) * sc[t] + bb[t];
  out[(size_t)e * 256 + t] = f2bf(nv * sigm(nv));
}

// --------------------- Wigner forward (MFMA, permuted) ---------------------
// B-fragments read DIRECTLY from global xT (L3-hot); only W stages via LDS.
// Overall column c in [0,256): node = (c<128 ? src : dst); within-node column
// is c & 127 (xT has 128 channels per node).
__global__ __launch_bounds__(256) void k_wig_fwd(
    const u16* __restrict__ xT, const int* __restrict__ eidx,
    const float* __restrict__ wig, const u16* __restrict__ xrad,
    u16* __restrict__ msgS, const int* __restrict__ perm, int e0)
{
  __shared__ u16 WL[32 * 64];
  int el = blockIdx.x, tid = threadIdx.x;
  int eg = perm[e0 + el];
  int lane = tid & 63, w = tid >> 6;

  const float* wp = wig + (size_t)eg * 1421;
  for (int idx = tid; idx < 2048; idx += 256){
    int m = idx >> 6, k = idx & 63;
    float v = (m < 29 && k < 49) ? wp[m * 49 + k] : 0.f;
    WL[m * 64 + ((((k >> 3) ^ (m & 7))) << 3) + (k & 7)] = f2bf(v);
  }

  const int fr = lane & 15, fq = lane >> 4;
  const int colbase = w * 64;
  int node = eidx[((w >> 1) ? E_NUM : 0) + eg];
  const u16* xb = xT + (size_t)node * 8192;
  bf16x8 bfv[4][2];
  #pragma unroll
  for (int ct = 0; ct < 4; ++ct)
    #pragma unroll
    for (int ks = 0; ks < 2; ++ks){
      int cc = ((w & 1) * 64) + ct * 16 + fr;       // within-node column
      bfv[ct][ks] = __builtin_bit_cast(bf16x8,
          *(const u16x8*)(xb + cc * 64 + (ks * 4 + fq) * 8));
    }
  __syncthreads();

  bf16x8 af[2][2];
  #pragma unroll
  for (int mt = 0; mt < 2; ++mt)
    #pragma unroll
    for (int ks = 0; ks < 2; ++ks){
      int m = mt * 16 + fr;
      int g = ks * 4 + fq;
      af[mt][ks] = __builtin_bit_cast(bf16x8,
          *(const u16x8*)&WL[m * 64 + ((g ^ (m & 7)) << 3)]);
    }
  f32x4 acc[2][4];
  #pragma unroll
  for (int mt = 0; mt < 2; ++mt)
    #pragma unroll
    for (int ct = 0; ct < 4; ++ct) acc[mt][ct] = (f32x4){0.f,0.f,0.f,0.f};
  #pragma unroll
  for (int mt = 0; mt < 2; ++mt)
    #pragma unroll
    for (int ct = 0; ct < 4; ++ct)
      #pragma unroll
      for (int ks = 0; ks < 2; ++ks)
        acc[mt][ct] = __builtin_amdgcn_mfma_f32_16x16x32_bf16(
            af[mt][ks], bfv[ct][ks], acc[mt][ct], 0, 0, 0);

  const u16* xr = xrad + (size_t)el * 4608;
  u16* o = msgS + (size_t)el * 7424;
  #pragma unroll
  for (int mt = 0; mt < 2; ++mt)
    #pragma unroll
    for (int ct = 0; ct < 4; ++ct){
      int col = colbase + ct * 16 + fr;
      #pragma unroll
      for (int r = 0; r < 4; ++r){
        int m = mt * 16 + fq * 4 + r;
        if (m < 29){
          int rr = (m < 13) ? m : (m < 24 ? m - 6 : m - 11);
          o[m * 256 + col] = f2bf(acc[mt][ct][r] * bf2f(xr[rr * 256 + col]));
        }
      }
    }
}

// ------------------------ gate + recombine (conv1) -------------------------
__global__ __launch_bounds__(128) void k_gate(
    const u16* __restrict__ c1m0, const u16* __restrict__ y10, const u16* __restrict__ y11,
    const u16* __restrict__ y20, const u16* __restrict__ y21, u16* __restrict__ msg2)
{
  int e = blockIdx.x, c = threadIdx.x;
  __shared__ float g[768];
  const u16* gp = c1m0 + (size_t)e * 1664;
  for (int i = c; i < 768; i += 128) g[i] = sigm(bf2f(gp[i]));
  __syncthreads();
  const u16* x0 = gp + 768;
  u16* o = msg2 + (size_t)e * 3712;
  { float v = bf2f(x0[c]); o[c] = f2bf(v * sigm(v)); }
  #pragma unroll
  for (int r = 1; r < 7; ++r)
    o[r * 128 + c] = f2bf(bf2f(x0[r * 128 + c]) * g[(r - 1) * 128 + c]);
  const u16* a0 = y10 + (size_t)e * 1536;
  const u16* a1 = y11 + (size_t)e * 1536;
  #pragma unroll
  for (int k = 0; k < 6; ++k){
    float orr = bf2f(a0[k * 128 + c]) - bf2f(a1[768 + k * 128 + c]);
    float oii = bf2f(a1[k * 128 + c]) + bf2f(a0[768 + k * 128 + c]);
    float gv = g[k * 128 + c];
    o[(7 + k)  * 128 + c] = f2bf(orr * gv);
    o[(13 + k) * 128 + c] = f2bf(oii * gv);
  }
  const u16* b0 = y20 + (size_t)e * 1280;
  const u16* b1 = y21 + (size_t)e * 1280;
  #pragma unroll
  for (int k = 0; k < 5; ++k){
    float orr = bf2f(b0[k * 128 + c]) - bf2f(b1[640 + k * 128 + c]);
    float oii = bf2f(b1[k * 128 + c]) + bf2f(b0[640 + k * 128 + c]);
    float gv = g[(1 + k) * 128 + c];
    o[(19 + k) * 128 + c] = f2bf(orr * gv);
    o[(24 + k) * 128 + c] = f2bf(oii * gv);
  }
}

// ------------- recombine2 + envelope -> TRANSPOSED msg3T (c,m) -------------
__global__ __launch_bounds__(128) void k_recomb2(
    const u16* __restrict__ m3x0, const u16* __restrict__ z10, const u16* __restrict__ z11,
    const u16* __restrict__ z20, const u16* __restrict__ z21, const float* __restrict__ env,
    u16* __restrict__ msg3T, const int* __restrict__ perm, int e0)
{
  int e = blockIdx.x, c = threadIdx.x;
  float ev = env[perm[e0 + e]];
  u16 v[32];
  const u16* x0 = m3x0 + (size_t)e * 896;
  #pragma unroll
  for (int r = 0; r < 7; ++r) v[r] = f2bf(bf2f(x0[r * 128 + c]) * ev);
  const u16* a0 = z10 + (size_t)e * 1536;
  const u16* a1 = z11 + (size_t)e * 1536;
  #pragma unroll
  for (int k = 0; k < 6; ++k){
    float orr = bf2f(a0[k * 128 + c]) - bf2f(a1[768 + k * 128 + c]);
    float oii = bf2f(a1[k * 128 + c]) + bf2f(a0[768 + k * 128 + c]);
    v[7 + k]  = f2bf(orr * ev);
    v[13 + k] = f2bf(oii * ev);
  }
  const u16* b0 = z20 + (size_t)e * 1280;
  const u16* b1 = z21 + (size_t)e * 1280;
  #pragma unroll
  for (int k = 0; k < 5; ++k){
    float orr = bf2f(b0[k * 128 + c]) - bf2f(b1[640 + k * 128 + c]);
    float oii = bf2f(b1[k * 128 + c]) + bf2f(b0[640 + k * 128 + c]);
    v[19 + k] = f2bf(orr * ev);
    v[24 + k] = f2bf(oii * ev);
  }
  v[29] = 0; v[30] = 0; v[31] = 0;
  u16* o = msg3T + (size_t)e * 4096 + c * 32;
  #pragma unroll
  for (int q = 0; q < 4; ++q)
    *(u16x8*)(o + q * 8) = *(const u16x8*)(&v[q * 8]);
}

// ------------- Wigner inverse (MFMA, run-gather) + scatter-add -------------
__global__ __launch_bounds__(256) void k_wig_inv(
    const u16* __restrict__ msg3T, const float* __restrict__ winv,
    const int* __restrict__ eidx, float* __restrict__ out,
    const int* __restrict__ perm, int e0, int cm)
{
  __shared__ u16 WV[64 * 32];
  int el = blockIdx.x, tid = threadIdx.x;
  int i = e0 + el;
  int d = eidx[E_NUM + perm[i]];
  if (el > 0 && eidx[E_NUM + perm[i - 1]] == d) return;   // not a run start
  int lane = tid & 63, w = tid >> 6;
  const int fr = lane & 15, fq = lane >> 4;
  const int jr = w * 16 + fr;

  f32x4 acc[8];
  #pragma unroll
  for (int ct = 0; ct < 8; ++ct) acc[ct] = (f32x4){0.f,0.f,0.f,0.f};

  int tend = e0 + cm;
  for (int t = i; t < tend; ++t){
    int pe = perm[t];
    if (t > i && eidx[E_NUM + pe] != d) break;
    __syncthreads();
    const float* wp = winv + (size_t)pe * 1421;
    for (int idx = tid; idx < 2048; idx += 256){
      int j = idx >> 5, m = idx & 31;
      float v = (j < 49 && m < 29) ? wp[j * 29 + m] : 0.f;
      WV[j * 32 + (((m >> 3) ^ (j & 3)) << 3) + (m & 7)] = f2bf(v);
    }
    __syncthreads();
    bf16x8 a = __builtin_bit_cast(bf16x8,
        *(const u16x8*)&WV[jr * 32 + ((fq ^ (jr & 3)) << 3)]);
    const u16* bp = msg3T + (size_t)(t - e0) * 4096;
    #pragma unroll
    for (int ct = 0; ct < 8; ++ct){
      bf16x8 b = __builtin_bit_cast(bf16x8,
          *(const u16x8*)(bp + (ct * 16 + fr) * 32 + fq * 8));
      acc[ct] = __builtin_amdgcn_mfma_f32_16x16x32_bf16(a, b, acc[ct], 0, 0, 0);
    }
  }

  float* op = out + (size_t)d * 6272;
  #pragma unroll
  for (int ct = 0; ct < 8; ++ct){
    int c = ct * 16 + fr;
    #pragma unroll
    for (int r = 0; r < 4; ++r){
      int j = w * 16 + fq * 4 + r;
      if (j < 49) atomicAdd(op + j * 128 + c, acc[ct][r]);
    }
  }
}

// ---------------------------------------------------------------------------
extern "C" void kernel_launch(void* const* d_in, const int* in_sizes, int n_in,
                              void* d_out, int out_size, void* d_ws, size_t ws_size,
                              hipStream_t stream)
{
  (void)in_sizes; (void)n_in;
  const float* x       = (const float*)d_in[0];
  const float* x_edge  = (const float*)d_in[1];
  const int*   eidx    = (const int*)d_in[3];
  const float* wig     = (const float*)d_in[4];
  const float* wig_inv = (const float*)d_in[5];
  const float* env     = (const float*)d_in[6];
  const float* rad_w0  = (const float*)d_in[7];
  const float* rad_b0  = (const float*)d_in[8];
  const float* ln0_s   = (const float*)d_in[9];
  const float* ln0_b   = (const float*)d_in[10];
  const float* rad_w1  = (const float*)d_in[11];
  const float* rad_b1  = (const float*)d_in[12];
  const float* ln1_s   = (const float*)d_in[13];
  const float* ln1_b   = (const float*)d_in[14];
  const float* rad_w2  = (const float*)d_in[15];
  const float* rad_b2  = (const float*)d_in[16];
  const float* c1w0    = (const float*)d_in[17];
  const float* c1b0    = (const float*)d_in[18];
  const float* c1w1    = (const float*)d_in[19];
  const float* c1w2    = (const float*)d_in[20];
  const float* c2w0    = (const float*)d_in[21];
  const float* c2b0    = (const float*)d_in[22];
  const float* c2w1    = (const float*)d_in[23];
  const float* c2w2    = (const float*)d_in[24];
  float* out = (float*)d_out;

  char* base = (char*)d_ws;
  size_t off = 0;
  auto alloc = [&](size_t bytes) -> char* {
    off = (off + 255) & ~(size_t)255;
    char* r = base + off;
    off += bytes;
    return r;
  };

  // ---- fixed area: bf16 weights (~22.2 MB) + xT (78 MB) + sort arrays ----
  u16* wtR0  = (u16*)alloc((size_t)256  * 128  * 2);
  u16* wtR1  = (u16*)alloc((size_t)256  * 256  * 2);
  u16* wtR2  = (u16*)alloc((size_t)4608 * 256  * 2);
  u16* wtC10 = (u16*)alloc((size_t)1664 * 1792 * 2);
  u16* wtC11 = (u16*)alloc((size_t)1536 * 1536 * 2);
  u16* wtC12 = (u16*)alloc((size_t)1280 * 1280 * 2);
  u16* wtC20 = (u16*)alloc((size_t)896  * 896  * 2);
  u16* wtC21 = (u16*)alloc((size_t)1536 * 768  * 2);
  u16* wtC22 = (u16*)alloc((size_t)1280 * 640  * 2);
  u16* xT    = (u16*)alloc((size_t)NN * 8192 * 2);
  int* cnt   = (int*)alloc(NN * 4);
  int* soff  = (int*)alloc(NN * 4);
  int* perm  = (int*)alloc(E_NUM * 4);

  // ---- chunk size from remaining workspace (40,960 B per edge) ----
  size_t fixed_end = (off + 65536) & ~(size_t)65535;
  size_t avail = (ws_size > fixed_end + (1u << 20)) ? (ws_size - fixed_end - (1u << 20)) : 0;
  long CH0 = (long)(avail / 40960);
  if (CH0 > E_NUM) CH0 = E_NUM;
  if (CH0 < 64) CH0 = 64;
  int nch = (int)((E_NUM + CH0 - 1) / CH0);
  int CH = (E_NUM + nch - 1) / nch;          // equalized chunks
  if (CH > CH0) CH = (int)CH0;

  off = fixed_end;
  const size_t C = (size_t)CH;
  u16*   xe   = (u16*)alloc(C * 128 * 2);
  float* tmp  = (float*)alloc(C * 256 * 4);
  u16*   h0   = (u16*)alloc(C * 256 * 2);
  u16*   h1   = (u16*)alloc(C * 256 * 2);
  u16* region1 = (u16*)alloc(C * 4608 * 2);   // xrad -> msg2
  u16* region2 = (u16*)alloc(C * 7424 * 2);   // msgS -> conv2 outs
  u16* region3 = (u16*)alloc(C * 7296 * 2);   // conv1 outs -> msg3T
  u16* xrad = region1;
  u16* msg2 = region1;
  u16* msgS = region2;
  u16* m3x0 = region2;                 // (C,896)
  u16* z10  = region2 + C * 896;       // (C,1536)
  u16* z11  = region2 + C * 2432;      // (C,1536)
  u16* z20  = region2 + C * 3968;      // (C,1280)
  u16* z21  = region2 + C * 5248;      // (C,1280)
  u16* c1m0b = region3;                // (C,1664)
  u16* y10   = region3 + C * 1664;     // (C,1536)
  u16* y11   = region3 + C * 3200;     // (C,1536)
  u16* y20   = region3 + C * 4736;     // (C,1280)
  u16* y21   = region3 + C * 6016;     // (C,1280)
  u16* msg3T = region3;                // (C,4096) transposed (c,m)

  hipMemsetAsync(d_out, 0, (size_t)out_size * sizeof(float), stream);
  hipMemsetAsync(cnt, 0, NN * 4, stream);

  // dst counting sort -> perm ; x transpose
  k_hist<<<(E_NUM + 255) / 256, 256, 0, stream>>>(eidx, cnt);
  k_scan<<<1, 256, 0, stream>>>(cnt, soff);
  k_scatter<<<(E_NUM + 255) / 256, 256, 0, stream>>>(eidx, soff, perm);
  k_xpose<<<NN, 256, 0, stream>>>(x, xT);

  auto tw = [&](const float* in, u16* o, int K, int N){
    k_transpose_w<<<dim3(N / 32, K / 32), 256, 0, stream>>>(in, o, K, N);
  };
  tw(rad_w0, wtR0, 128, 256);
  tw(rad_w1, wtR1, 256, 256);
  tw(rad_w2, wtR2, 256, 4608);
  tw(c1w0, wtC10, 1792, 1664);
  tw(c1w1, wtC11, 1536, 1536);
  tw(c1w2, wtC12, 1280, 1280);
  tw(c2w0, wtC20, 896, 896);
  tw(c2w1, wtC21, 768, 1536);
  tw(c2w2, wtC22, 640, 1280);

  auto gemm = [&](const u16* A, const u16* A2, int lda, const u16* B,
                  const float* bias, float* Cf, u16* Cb, u16* Cb2,
                  int ldc, int M, int N, int K){
    int myb = (M + 127) / 128;
    k_gemm_bt<<<dim3(N / 128, A2 ? 2 * myb : myb), 256, 0, stream>>>(
        A, A2, lda, B, bias, Cf, Cb, Cb2, ldc, M, N, K, myb);
  };

  for (int e0 = 0; e0 < E_NUM; e0 += CH){
    int cm = E_NUM - e0 < CH ? E_NUM - e0 : CH;

    k_gather_xe<<<cm, 128, 0, stream>>>(x_edge, perm, xe, e0);

    // radial MLP
    gemm(xe, nullptr, 128, wtR0, rad_b0, tmp, nullptr, nullptr, 256, cm, 256, 128);
    k_ln_silu<<<cm, 256, 0, stream>>>(tmp, ln0_s, ln0_b, h0);
    gemm(h0, nullptr, 256, wtR1, rad_b1, tmp, nullptr, nullptr, 256, cm, 256, 256);
    k_ln_silu<<<cm, 256, 0, stream>>>(tmp, ln1_s, ln1_b, h1);
    gemm(h1, nullptr, 256, wtR2, rad_b2, nullptr, xrad, nullptr, 4608, cm, 4608, 256);

    // wigner forward (MFMA, B-frags from global xT)
    k_wig_fwd<<<cm, 256, 0, stream>>>(xT, eidx, wig, xrad, msgS, perm, e0);

    // conv1 (m0 + two weight-shared pairs)
    gemm(msgS,        nullptr,      7424, wtC10, c1b0,
         nullptr, c1m0b, nullptr, 1664, cm, 1664, 1792);
    gemm(msgS + 1792, msgS + 3328,  7424, wtC11, nullptr,
         nullptr, y10, y11, 1536, cm, 1536, 1536);
    gemm(msgS + 4864, msgS + 6144,  7424, wtC12, nullptr,
         nullptr, y20, y21, 1280, cm, 1280, 1280);

    k_gate<<<cm, 128, 0, stream>>>(c1m0b, y10, y11, y20, y21, msg2);

    // conv2 (m0 + two weight-shared pairs)
    gemm(msg2,        nullptr,      3712, wtC20, c2b0,
         nullptr, m3x0, nullptr, 896, cm, 896, 896);
    gemm(msg2 + 896,  msg2 + 1664,  3712, wtC21, nullptr,
         nullptr, z10, z11, 1536, cm, 1536, 768);
    gemm(msg2 + 2432, msg2 + 3072,  3712, wtC22, nullptr,
         nullptr, z20, z21, 1280, cm, 1280, 640);

    k_recomb2<<<cm, 128, 0, stream>>>(m3x0, z10, z11, z20, z21, env, msg3T, perm, e0);

    // wigner inverse + run-gather scatter (MFMA)
    k_wig_inv<<<cm, 256, 0, stream>>>(msg3T, wig_inv, eidx, out, perm, e0, cm);
  }
}

// Round 9
// 2438.063 us; speedup vs baseline: 1.6690x; 1.0342x over previous
//
#include <hip/hip_runtime.h>
#include <stdint.h>

// ---------------------------------------------------------------------------
// Edgewise (eSCN SO(2) conv block), MI355X gfx950.
// Round 9: conv1/conv2 GEMMs merged into single segmented launches (tail
// overlap, fewer launch bubbles) + bijective XCD swizzle on the GEMM grid.
// Otherwise identical to round 8 (dbuf GEMM, xT, dst-sorted run-gather).
// ---------------------------------------------------------------------------

#define E_NUM   20000
#define NN      5000

typedef uint16_t u16;
typedef __bf16  bf16x8 __attribute__((ext_vector_type(8)));
typedef float   f32x4  __attribute__((ext_vector_type(4)));
typedef uint16_t u16x8 __attribute__((ext_vector_type(8)));

__device__ __forceinline__ float bf2f(u16 h){
  uint32_t u = ((uint32_t)h) << 16;
  return __builtin_bit_cast(float, u);
}
__device__ __forceinline__ u16 f2bf(float f){
  uint32_t u = __builtin_bit_cast(uint32_t, f);
  u += 0x7fffu + ((u >> 16) & 1u);
  return (u16)(u >> 16);
}
__device__ __forceinline__ float sigm(float x){ return 1.f / (1.f + __expf(-x)); }

__device__ __forceinline__ void gload16(const void* g, void* l){
  __builtin_amdgcn_global_load_lds(
      (const __attribute__((address_space(1))) void*)g,
      (__attribute__((address_space(3))) void*)l, 16, 0, 0);
}

// bijective XCD swizzle (m204): contiguous wgid ranges per XCD
__device__ __forceinline__ int swz8(int orig, int nwg){
  int q = nwg >> 3, r = nwg & 7;
  int x = orig & 7, p = orig >> 3;
  int base = (x < r) ? x * (q + 1) : r * (q + 1) + (x - r) * q;
  return base + p;
}

// ----------------------- dst counting sort ---------------------------------
__global__ void k_hist(const int* __restrict__ eidx, int* __restrict__ cnt){
  int e = blockIdx.x * 256 + threadIdx.x;
  if (e < E_NUM) atomicAdd(&cnt[eidx[E_NUM + e]], 1);
}
__global__ __launch_bounds__(256) void k_scan(const int* __restrict__ cnt,
                                              int* __restrict__ off){
  __shared__ int part[256];
  int t = threadIdx.x;
  int s = 0;
  #pragma unroll
  for (int i = 0; i < 20; ++i){
    int idx = t * 20 + i;
    if (idx < NN) s += cnt[idx];
  }
  part[t] = s;
  __syncthreads();
  if (t == 0){
    int run = 0;
    for (int i = 0; i < 256; ++i){ int v = part[i]; part[i] = run; run += v; }
  }
  __syncthreads();
  int run = part[t];
  #pragma unroll
  for (int i = 0; i < 20; ++i){
    int idx = t * 20 + i;
    if (idx < NN){ off[idx] = run; run += cnt[idx]; }
  }
}
__global__ void k_scatter(const int* __restrict__ eidx, int* __restrict__ off,
                          int* __restrict__ perm){
  int e = blockIdx.x * 256 + threadIdx.x;
  if (e < E_NUM){
    int pos = atomicAdd(&off[eidx[E_NUM + e]], 1);
    perm[pos] = e;
  }
}

// --------------------------- weight transpose ------------------------------
__global__ void k_transpose_w(const float* __restrict__ in, u16* __restrict__ out,
                              int K, int N){
  __shared__ float t[32][33];
  int nb = blockIdx.x * 32, kb = blockIdx.y * 32;
  int tx = threadIdx.x & 31, ty = threadIdx.x >> 5;   // 32x8
  for (int i = ty; i < 32; i += 8)
    t[i][tx] = in[(size_t)(kb + i) * N + (nb + tx)];
  __syncthreads();
  for (int i = ty; i < 32; i += 8)
    out[(size_t)(nb + i) * K + (kb + tx)] = f2bf(t[tx][i]);
}

// ------------- x -> xT bf16, [node][c=128][k=64 padded], once --------------
__global__ __launch_bounds__(256) void k_xpose(const float* __restrict__ x,
                                               u16* __restrict__ xT){
  __shared__ float t[6272];
  int n = blockIdx.x, tid = threadIdx.x;
  const float* xp = x + (size_t)n * 6272;
  for (int i = tid; i < 6272; i += 256) t[i] = xp[i];
  __syncthreads();
  int c = tid >> 1;
  int kh = (tid & 1) * 32;
  u16* o = xT + (size_t)n * 8192 + c * 64 + kh;
  #pragma unroll
  for (int q = 0; q < 4; ++q){
    u16x8 h;
    #pragma unroll
    for (int i = 0; i < 8; ++i){
      int k = kh + q * 8 + i;
      h[i] = (k < 49) ? f2bf(t[k * 128 + c]) : (u16)0;
    }
    *(u16x8*)(o + q * 8) = h;
  }
}

// gather x_edge rows in permuted order -> bf16
__global__ void k_gather_xe(const float* __restrict__ x_edge,
                            const int* __restrict__ perm,
                            u16* __restrict__ xe, int e0){
  int el = blockIdx.x, c = threadIdx.x;
  int pe = perm[e0 + el];
  xe[(size_t)el * 128 + c] = f2bf(x_edge[(size_t)pe * 128 + c]);
}

// ---------------------- GEMM core (shared by both kernels) -----------------
// Computes one 128x128 C-tile of A(M,K)@B^T with dbuf LDS; bf16 out (Cb) or
// f32 (Cf). Must be called with uniform (A,B,bias,...) across the block.
struct Seg {
  const u16* A; const u16* B; u16* C; const float* bias;
  int M, N, K, lda, blk0;
};
struct Seg5 { Seg s[5]; int nwg; };

__device__ __forceinline__ void gemm_tile(
    const u16* __restrict__ A, int lda, const u16* __restrict__ B,
    const float* __restrict__ bias, float* __restrict__ Cf,
    u16* __restrict__ Cb, int ldc, int M, int N, int K,
    int bm, int bn, u16* As /*2*4096*/, u16* Bs /*2*4096*/)
{
  const int tid  = threadIdx.x;
  const int lane = tid & 63;
  const int wave = tid >> 6;
  const int wm = wave >> 1, wn = wave & 1;
  const int fr = lane & 15, fq = lane >> 4;
  const int row0 = bm * 128;

  const int lr  = lane >> 2;
  const int lg  = lane & 3;
  const int rA0 = wave * 32 + lr;
  const int rA1 = rA0 + 16;
  const int g0  = lg ^ ((rA0 >> 1) & 3);
  const int g1  = lg ^ ((rA1 >> 1) & 3);
  int gra0 = row0 + rA0; if (gra0 > M - 1) gra0 = M - 1;
  int gra1 = row0 + rA1; if (gra1 > M - 1) gra1 = M - 1;
  const u16* aS0 = A + (size_t)gra0 * lda + g0 * 8;
  const u16* aS1 = A + (size_t)gra1 * lda + g1 * 8;
  const u16* bS0 = B + (size_t)(bn * 128 + rA0) * K + g0 * 8;
  const u16* bS1 = B + (size_t)(bn * 128 + rA1) * K + g1 * 8;
  const int dA0 = (wave * 32) * 32;
  const int dA1 = (wave * 32 + 16) * 32;

  int aoff[4], boff[4];
  #pragma unroll
  for (int mi = 0; mi < 4; ++mi){
    int r = wm * 64 + mi * 16 + fr;
    aoff[mi] = r * 32 + (fq ^ ((r >> 1) & 3)) * 8;
  }
  #pragma unroll
  for (int ni = 0; ni < 4; ++ni){
    int r = wn * 64 + ni * 16 + fr;
    boff[ni] = r * 32 + (fq ^ ((r >> 1) & 3)) * 8;
  }

  f32x4 acc[4][4];
  #pragma unroll
  for (int i = 0; i < 4; ++i)
    #pragma unroll
    for (int j = 0; j < 4; ++j) acc[i][j] = (f32x4){0.f, 0.f, 0.f, 0.f};

  auto stage = [&](int buf, int k0){
    gload16(aS0 + k0, &As[buf * 4096 + dA0]);
    gload16(aS1 + k0, &As[buf * 4096 + dA1]);
    gload16(bS0 + k0, &Bs[buf * 4096 + dA0]);
    gload16(bS1 + k0, &Bs[buf * 4096 + dA1]);
  };

  stage(0, 0);
  __syncthreads();
  int cur = 0;
  for (int k0 = 0; k0 < K; k0 += 32){
    if (k0 + 32 < K) stage(cur ^ 1, k0 + 32);
    bf16x8 af[4], bfv[4];
    #pragma unroll
    for (int mi = 0; mi < 4; ++mi)
      af[mi] = __builtin_bit_cast(bf16x8, *(const u16x8*)&As[cur * 4096 + aoff[mi]]);
    #pragma unroll
    for (int ni = 0; ni < 4; ++ni)
      bfv[ni] = __builtin_bit_cast(bf16x8, *(const u16x8*)&Bs[cur * 4096 + boff[ni]]);
    #pragma unroll
    for (int mi = 0; mi < 4; ++mi)
      #pragma unroll
      for (int ni = 0; ni < 4; ++ni)
        acc[mi][ni] = __builtin_amdgcn_mfma_f32_16x16x32_bf16(af[mi], bfv[ni], acc[mi][ni], 0, 0, 0);
    __syncthreads();          // drains vmcnt(0): next buffer landed
    cur ^= 1;
  }

  #pragma unroll
  for (int ni = 0; ni < 4; ++ni){
    int col = bn * 128 + wn * 64 + ni * 16 + fr;
    float bv = bias ? bias[col] : 0.f;
    #pragma unroll
    for (int mi = 0; mi < 4; ++mi){
      #pragma unroll
      for (int i = 0; i < 4; ++i){
        int row = row0 + wm * 64 + mi * 16 + fq * 4 + i;
        if (row < M){
          float v = acc[mi][ni][i] + bv;
          if (Cb) Cb[(size_t)row * ldc + col] = f2bf(v);
          else    Cf[(size_t)row * ldc + col] = v;
        }
      }
    }
  }
}

// plain GEMM (radial MLP); ldc == N
__global__ __launch_bounds__(256) void k_gemm_bt(
    const u16* __restrict__ A, int lda, const u16* __restrict__ B,
    const float* __restrict__ bias, float* __restrict__ Cf,
    u16* __restrict__ Cb, int ldc, int M, int N, int K)
{
  __shared__ u16 As[2 * 4096];
  __shared__ u16 Bs[2 * 4096];
  gemm_tile(A, lda, B, bias, Cf, Cb, ldc, M, N, K,
            blockIdx.y, blockIdx.x, As, Bs);
}

// segmented GEMM: up to 5 independent (A,B,C) GEMMs in one launch.
// All C outputs bf16, ldc = N per segment; XCD-swizzled flat grid.
__global__ __launch_bounds__(256) void k_gemm_seg(Seg5 g)
{
  __shared__ u16 As[2 * 4096];
  __shared__ u16 Bs[2 * 4096];
  int wgid = swz8(blockIdx.x, g.nwg);
  Seg sg = g.s[4];
  if (wgid < g.s[4].blk0) sg = g.s[3];
  if (wgid < g.s[3].blk0) sg = g.s[2];
  if (wgid < g.s[2].blk0) sg = g.s[1];
  if (wgid < g.s[1].blk0) sg = g.s[0];
  int local = wgid - sg.blk0;
  int nbx = sg.N >> 7;
  int bn = local % nbx;
  int bm = local / nbx;
  gemm_tile(sg.A, sg.lda, sg.B, sg.bias, nullptr, sg.C, sg.N,
            sg.M, sg.N, sg.K, bm, bn, As, Bs);
}

// --------------------------- LayerNorm + SiLU ------------------------------
__global__ __launch_bounds__(256) void k_ln_silu(
    const float* __restrict__ in, const float* __restrict__ sc,
    const float* __restrict__ bb, u16* __restrict__ out)
{
  int e = blockIdx.x, t = threadIdx.x;
  float v = in[(size_t)e * 256 + t];
  float s1 = v, s2 = v * v;
  #pragma unroll
  for (int off = 32; off > 0; off >>= 1){
    s1 += __shfl_down(s1, off);
    s2 += __shfl_down(s2, off);
  }
  __shared__ float r1[4], r2[4];
  if ((t & 63) == 0){ r1[t >> 6] = s1; r2[t >> 6] = s2; }
  __syncthreads();
  float S1 = r1[0] + r1[1] + r1[2] + r1[3];
  float S2 = r2[0] + r2[1] + r2[2] + r2[3];
  float mu  = S1 * (1.f / 256.f);
  float var = S2 * (1.f / 256.f) - mu * mu;
  float nv = (v - mu) * rsqrtf(var + 1e-5f) * sc[t] + bb[t];
  out[(size_t)e * 256 + t] = f2bf(nv * sigm(nv));
}

// --------------------- Wigner forward (MFMA, permuted) ---------------------
__global__ __launch_bounds__(256) void k_wig_fwd(
    const u16* __restrict__ xT, const int* __restrict__ eidx,
    const float* __restrict__ wig, const u16* __restrict__ xrad,
    u16* __restrict__ msgS, const int* __restrict__ perm, int e0)
{
  __shared__ u16 WL[32 * 64];
  int el = blockIdx.x, tid = threadIdx.x;
  int eg = perm[e0 + el];
  int lane = tid & 63, w = tid >> 6;

  const float* wp = wig + (size_t)eg * 1421;
  for (int idx = tid; idx < 2048; idx += 256){
    int m = idx >> 6, k = idx & 63;
    float v = (m < 29 && k < 49) ? wp[m * 49 + k] : 0.f;
    WL[m * 64 + ((((k >> 3) ^ (m & 7))) << 3) + (k & 7)] = f2bf(v);
  }

  const int fr = lane & 15, fq = lane >> 4;
  const int colbase = w * 64;
  int node = eidx[((w >> 1) ? E_NUM : 0) + eg];
  const u16* xb = xT + (size_t)node * 8192;
  bf16x8 bfv[4][2];
  #pragma unroll
  for (int ct = 0; ct < 4; ++ct)
    #pragma unroll
    for (int ks = 0; ks < 2; ++ks){
      int cc = ((w & 1) * 64) + ct * 16 + fr;       // within-node column
      bfv[ct][ks] = __builtin_bit_cast(bf16x8,
          *(const u16x8*)(xb + cc * 64 + (ks * 4 + fq) * 8));
    }
  __syncthreads();

  bf16x8 af[2][2];
  #pragma unroll
  for (int mt = 0; mt < 2; ++mt)
    #pragma unroll
    for (int ks = 0; ks < 2; ++ks){
      int m = mt * 16 + fr;
      int g = ks * 4 + fq;
      af[mt][ks] = __builtin_bit_cast(bf16x8,
          *(const u16x8*)&WL[m * 64 + ((g ^ (m & 7)) << 3)]);
    }
  f32x4 acc[2][4];
  #pragma unroll
  for (int mt = 0; mt < 2; ++mt)
    #pragma unroll
    for (int ct = 0; ct < 4; ++ct) acc[mt][ct] = (f32x4){0.f,0.f,0.f,0.f};
  #pragma unroll
  for (int mt = 0; mt < 2; ++mt)
    #pragma unroll
    for (int ct = 0; ct < 4; ++ct)
      #pragma unroll
      for (int ks = 0; ks < 2; ++ks)
        acc[mt][ct] = __builtin_amdgcn_mfma_f32_16x16x32_bf16(
            af[mt][ks], bfv[ct][ks], acc[mt][ct], 0, 0, 0);

  const u16* xr = xrad + (size_t)el * 4608;
  u16* o = msgS + (size_t)el * 7424;
  #pragma unroll
  for (int mt = 0; mt < 2; ++mt)
    #pragma unroll
    for (int ct = 0; ct < 4; ++ct){
      int col = colbase + ct * 16 + fr;
      #pragma unroll
      for (int r = 0; r < 4; ++r){
        int m = mt * 16 + fq * 4 + r;
        if (m < 29){
          int rr = (m < 13) ? m : (m < 24 ? m - 6 : m - 11);
          o[m * 256 + col] = f2bf(acc[mt][ct][r] * bf2f(xr[rr * 256 + col]));
        }
      }
    }
}

// ------------------------ gate + recombine (conv1) -------------------------
__global__ __launch_bounds__(128) void k_gate(
    const u16* __restrict__ c1m0, const u16* __restrict__ y10, const u16* __restrict__ y11,
    const u16* __restrict__ y20, const u16* __restrict__ y21, u16* __restrict__ msg2)
{
  int e = blockIdx.x, c = threadIdx.x;
  __shared__ float g[768];
  const u16* gp = c1m0 + (size_t)e * 1664;
  for (int i = c; i < 768; i += 128) g[i] = sigm(bf2f(gp[i]));
  __syncthreads();
  const u16* x0 = gp + 768;
  u16* o = msg2 + (size_t)e * 3712;
  { float v = bf2f(x0[c]); o[c] = f2bf(v * sigm(v)); }
  #pragma unroll
  for (int r = 1; r < 7; ++r)
    o[r * 128 + c] = f2bf(bf2f(x0[r * 128 + c]) * g[(r - 1) * 128 + c]);
  const u16* a0 = y10 + (size_t)e * 1536;
  const u16* a1 = y11 + (size_t)e * 1536;
  #pragma unroll
  for (int k = 0; k < 6; ++k){
    float orr = bf2f(a0[k * 128 + c]) - bf2f(a1[768 + k * 128 + c]);
    float oii = bf2f(a1[k * 128 + c]) + bf2f(a0[768 + k * 128 + c]);
    float gv = g[k * 128 + c];
    o[(7 + k)  * 128 + c] = f2bf(orr * gv);
    o[(13 + k) * 128 + c] = f2bf(oii * gv);
  }
  const u16* b0 = y20 + (size_t)e * 1280;
  const u16* b1 = y21 + (size_t)e * 1280;
  #pragma unroll
  for (int k = 0; k < 5; ++k){
    float orr = bf2f(b0[k * 128 + c]) - bf2f(b1[640 + k * 128 + c]);
    float oii = bf2f(b1[k * 128 + c]) + bf2f(b0[640 + k * 128 + c]);
    float gv = g[(1 + k) * 128 + c];
    o[(19 + k) * 128 + c] = f2bf(orr * gv);
    o[(24 + k) * 128 + c] = f2bf(oii * gv);
  }
}

// ------------- recombine2 + envelope -> TRANSPOSED msg3T (c,m) -------------
__global__ __launch_bounds__(128) void k_recomb2(
    const u16* __restrict__ m3x0, const u16* __restrict__ z10, const u16* __restrict__ z11,
    const u16* __restrict__ z20, const u16* __restrict__ z21, const float* __restrict__ env,
    u16* __restrict__ msg3T, const int* __restrict__ perm, int e0)
{
  int e = blockIdx.x, c = threadIdx.x;
  float ev = env[perm[e0 + e]];
  u16 v[32];
  const u16* x0 = m3x0 + (size_t)e * 896;
  #pragma unroll
  for (int r = 0; r < 7; ++r) v[r] = f2bf(bf2f(x0[r * 128 + c]) * ev);
  const u16* a0 = z10 + (size_t)e * 1536;
  const u16* a1 = z11 + (size_t)e * 1536;
  #pragma unroll
  for (int k = 0; k < 6; ++k){
    float orr = bf2f(a0[k * 128 + c]) - bf2f(a1[768 + k * 128 + c]);
    float oii = bf2f(a1[k * 128 + c]) + bf2f(a0[768 + k * 128 + c]);
    v[7 + k]  = f2bf(orr * ev);
    v[13 + k] = f2bf(oii * ev);
  }
  const u16* b0 = z20 + (size_t)e * 1280;
  const u16* b1 = z21 + (size_t)e * 1280;
  #pragma unroll
  for (int k = 0; k < 5; ++k){
    float orr = bf2f(b0[k * 128 + c]) - bf2f(b1[640 + k * 128 + c]);
    float oii = bf2f(b1[k * 128 + c]) + bf2f(b0[640 + k * 128 + c]);
    v[19 + k] = f2bf(orr * ev);
    v[24 + k] = f2bf(oii * ev);
  }
  v[29] = 0; v[30] = 0; v[31] = 0;
  u16* o = msg3T + (size_t)e * 4096 + c * 32;
  #pragma unroll
  for (int q = 0; q < 4; ++q)
    *(u16x8*)(o + q * 8) = *(const u16x8*)(&v[q * 8]);
}

// ------------- Wigner inverse (MFMA, run-gather) + scatter-add -------------
__global__ __launch_bounds__(256) void k_wig_inv(
    const u16* __restrict__ msg3T, const float* __restrict__ winv,
    const int* __restrict__ eidx, float* __restrict__ out,
    const int* __restrict__ perm, int e0, int cm)
{
  __shared__ u16 WV[64 * 32];
  int el = blockIdx.x, tid = threadIdx.x;
  int i = e0 + el;
  int d = eidx[E_NUM + perm[i]];
  if (el > 0 && eidx[E_NUM + perm[i - 1]] == d) return;   // not a run start
  int lane = tid & 63, w = tid >> 6;
  const int fr = lane & 15, fq = lane >> 4;
  const int jr = w * 16 + fr;

  f32x4 acc[8];
  #pragma unroll
  for (int ct = 0; ct < 8; ++ct) acc[ct] = (f32x4){0.f,0.f,0.f,0.f};

  int tend = e0 + cm;
  for (int t = i; t < tend; ++t){
    int pe = perm[t];
    if (t > i && eidx[E_NUM + pe] != d) break;
    __syncthreads();
    const float* wp = winv + (size_t)pe * 1421;
    for (int idx = tid; idx < 2048; idx += 256){
      int j = idx >> 5, m = idx & 31;
      float v = (j < 49 && m < 29) ? wp[j * 29 + m] : 0.f;
      WV[j * 32 + (((m >> 3) ^ (j & 3)) << 3) + (m & 7)] = f2bf(v);
    }
    __syncthreads();
    bf16x8 a = __builtin_bit_cast(bf16x8,
        *(const u16x8*)&WV[jr * 32 + ((fq ^ (jr & 3)) << 3)]);
    const u16* bp = msg3T + (size_t)(t - e0) * 4096;
    #pragma unroll
    for (int ct = 0; ct < 8; ++ct){
      bf16x8 b = __builtin_bit_cast(bf16x8,
          *(const u16x8*)(bp + (ct * 16 + fr) * 32 + fq * 8));
      acc[ct] = __builtin_amdgcn_mfma_f32_16x16x32_bf16(a, b, acc[ct], 0, 0, 0);
    }
  }

  float* op = out + (size_t)d * 6272;
  #pragma unroll
  for (int ct = 0; ct < 8; ++ct){
    int c = ct * 16 + fr;
    #pragma unroll
    for (int r = 0; r < 4; ++r){
      int j = w * 16 + fq * 4 + r;
      if (j < 49) atomicAdd(op + j * 128 + c, acc[ct][r]);
    }
  }
}

// ---------------------------------------------------------------------------
extern "C" void kernel_launch(void* const* d_in, const int* in_sizes, int n_in,
                              void* d_out, int out_size, void* d_ws, size_t ws_size,
                              hipStream_t stream)
{
  (void)in_sizes; (void)n_in;
  const float* x       = (const float*)d_in[0];
  const float* x_edge  = (const float*)d_in[1];
  const int*   eidx    = (const int*)d_in[3];
  const float* wig     = (const float*)d_in[4];
  const float* wig_inv = (const float*)d_in[5];
  const float* env     = (const float*)d_in[6];
  const float* rad_w0  = (const float*)d_in[7];
  const float* rad_b0  = (const float*)d_in[8];
  const float* ln0_s   = (const float*)d_in[9];
  const float* ln0_b   = (const float*)d_in[10];
  const float* rad_w1  = (const float*)d_in[11];
  const float* rad_b1  = (const float*)d_in[12];
  const float* ln1_s   = (const float*)d_in[13];
  const float* ln1_b   = (const float*)d_in[14];
  const float* rad_w2  = (const float*)d_in[15];
  const float* rad_b2  = (const float*)d_in[16];
  const float* c1w0    = (const float*)d_in[17];
  const float* c1b0    = (const float*)d_in[18];
  const float* c1w1    = (const float*)d_in[19];
  const float* c1w2    = (const float*)d_in[20];
  const float* c2w0    = (const float*)d_in[21];
  const float* c2b0    = (const float*)d_in[22];
  const float* c2w1    = (const float*)d_in[23];
  const float* c2w2    = (const float*)d_in[24];
  float* out = (float*)d_out;

  char* base = (char*)d_ws;
  size_t off = 0;
  auto alloc = [&](size_t bytes) -> char* {
    off = (off + 255) & ~(size_t)255;
    char* r = base + off;
    off += bytes;
    return r;
  };

  // ---- fixed area: bf16 weights (~22.2 MB) + xT (78 MB) + sort arrays ----
  u16* wtR0  = (u16*)alloc((size_t)256  * 128  * 2);
  u16* wtR1  = (u16*)alloc((size_t)256  * 256  * 2);
  u16* wtR2  = (u16*)alloc((size_t)4608 * 256  * 2);
  u16* wtC10 = (u16*)alloc((size_t)1664 * 1792 * 2);
  u16* wtC11 = (u16*)alloc((size_t)1536 * 1536 * 2);
  u16* wtC12 = (u16*)alloc((size_t)1280 * 1280 * 2);
  u16* wtC20 = (u16*)alloc((size_t)896  * 896  * 2);
  u16* wtC21 = (u16*)alloc((size_t)1536 * 768  * 2);
  u16* wtC22 = (u16*)alloc((size_t)1280 * 640  * 2);
  u16* xT    = (u16*)alloc((size_t)NN * 8192 * 2);
  int* cnt   = (int*)alloc(NN * 4);
  int* soff  = (int*)alloc(NN * 4);
  int* perm  = (int*)alloc(E_NUM * 4);

  // ---- chunk size from remaining workspace (40,960 B per edge) ----
  size_t fixed_end = (off + 65536) & ~(size_t)65535;
  size_t avail = (ws_size > fixed_end + (1u << 20)) ? (ws_size - fixed_end - (1u << 20)) : 0;
  long CH0 = (long)(avail / 40960);
  if (CH0 > E_NUM) CH0 = E_NUM;
  if (CH0 < 64) CH0 = 64;
  int nch = (int)((E_NUM + CH0 - 1) / CH0);
  int CH = (E_NUM + nch - 1) / nch;          // equalized chunks
  if (CH > CH0) CH = (int)CH0;

  off = fixed_end;
  const size_t C = (size_t)CH;
  u16*   xe   = (u16*)alloc(C * 128 * 2);
  float* tmp  = (float*)alloc(C * 256 * 4);
  u16*   h0   = (u16*)alloc(C * 256 * 2);
  u16*   h1   = (u16*)alloc(C * 256 * 2);
  u16* region1 = (u16*)alloc(C * 4608 * 2);   // xrad -> msg2
  u16* region2 = (u16*)alloc(C * 7424 * 2);   // msgS -> conv2 outs
  u16* region3 = (u16*)alloc(C * 7296 * 2);   // conv1 outs -> msg3T
  u16* xrad = region1;
  u16* msg2 = region1;
  u16* msgS = region2;
  u16* m3x0 = region2;                 // (C,896)
  u16* z10  = region2 + C * 896;       // (C,1536)
  u16* z11  = region2 + C * 2432;      // (C,1536)
  u16* z20  = region2 + C * 3968;      // (C,1280)
  u16* z21  = region2 + C * 5248;      // (C,1280)
  u16* c1m0b = region3;                // (C,1664)
  u16* y10   = region3 + C * 1664;     // (C,1536)
  u16* y11   = region3 + C * 3200;     // (C,1536)
  u16* y20   = region3 + C * 4736;     // (C,1280)
  u16* y21   = region3 + C * 6016;     // (C,1280)
  u16* msg3T = region3;                // (C,4096) transposed (c,m)

  hipMemsetAsync(d_out, 0, (size_t)out_size * sizeof(float), stream);
  hipMemsetAsync(cnt, 0, NN * 4, stream);

  // dst counting sort -> perm ; x transpose
  k_hist<<<(E_NUM + 255) / 256, 256, 0, stream>>>(eidx, cnt);
  k_scan<<<1, 256, 0, stream>>>(cnt, soff);
  k_scatter<<<(E_NUM + 255) / 256, 256, 0, stream>>>(eidx, soff, perm);
  k_xpose<<<NN, 256, 0, stream>>>(x, xT);

  auto tw = [&](const float* in, u16* o, int K, int N){
    k_transpose_w<<<dim3(N / 32, K / 32), 256, 0, stream>>>(in, o, K, N);
  };
  tw(rad_w0, wtR0, 128, 256);
  tw(rad_w1, wtR1, 256, 256);
  tw(rad_w2, wtR2, 256, 4608);
  tw(c1w0, wtC10, 1792, 1664);
  tw(c1w1, wtC11, 1536, 1536);
  tw(c1w2, wtC12, 1280, 1280);
  tw(c2w0, wtC20, 896, 896);
  tw(c2w1, wtC21, 768, 1536);
  tw(c2w2, wtC22, 640, 1280);

  auto gemm = [&](const u16* A, int lda, const u16* B, const float* bias,
                  float* Cf, u16* Cb, int ldc, int M, int N, int K){
    k_gemm_bt<<<dim3(N / 128, (M + 127) / 128), 256, 0, stream>>>(
        A, lda, B, bias, Cf, Cb, ldc, M, N, K);
  };

  for (int e0 = 0; e0 < E_NUM; e0 += CH){
    int cm = E_NUM - e0 < CH ? E_NUM - e0 : CH;
    int mb = (cm + 127) / 128;

    k_gather_xe<<<cm, 128, 0, stream>>>(x_edge, perm, xe, e0);

    // radial MLP
    gemm(xe, 128, wtR0, rad_b0, tmp, nullptr, 256, cm, 256, 128);
    k_ln_silu<<<cm, 256, 0, stream>>>(tmp, ln0_s, ln0_b, h0);
    gemm(h0, 256, wtR1, rad_b1, tmp, nullptr, 256, cm, 256, 256);
    k_ln_silu<<<cm, 256, 0, stream>>>(tmp, ln1_s, ln1_b, h1);
    gemm(h1, 256, wtR2, rad_b2, nullptr, xrad, 4608, cm, 4608, 256);

    // wigner forward (MFMA, B-frags from global xT)
    k_wig_fwd<<<cm, 256, 0, stream>>>(xT, eidx, wig, xrad, msgS, perm, e0);

    // conv1: one segmented launch (m0 + y10 + y11 + y20 + y21)
    {
      Seg5 g;
      int b = 0;
      auto mk = [&](const u16* A, const u16* B, u16* Cb, const float* bias,
                    int N, int K) -> Seg {
        Seg s{A, B, Cb, bias, cm, N, K, 7424, b};
        b += (N >> 7) * mb;
        return s;
      };
      g.s[0] = mk(msgS,        wtC10, c1m0b, c1b0,   1664, 1792);
      g.s[1] = mk(msgS + 1792, wtC11, y10,   nullptr, 1536, 1536);
      g.s[2] = mk(msgS + 3328, wtC11, y11,   nullptr, 1536, 1536);
      g.s[3] = mk(msgS + 4864, wtC12, y20,   nullptr, 1280, 1280);
      g.s[4] = mk(msgS + 6144, wtC12, y21,   nullptr, 1280, 1280);
      g.nwg = b;
      k_gemm_seg<<<b, 256, 0, stream>>>(g);
    }

    k_gate<<<cm, 128, 0, stream>>>(c1m0b, y10, y11, y20, y21, msg2);

    // conv2: one segmented launch (m0 + z10 + z11 + z20 + z21)
    {
      Seg5 g;
      int b = 0;
      auto mk = [&](const u16* A, const u16* B, u16* Cb, const float* bias,
                    int N, int K) -> Seg {
        Seg s{A, B, Cb, bias, cm, N, K, 3712, b};
        b += (N >> 7) * mb;
        return s;
      };
      g.s[0] = mk(msg2,        wtC20, m3x0, c2b0,   896,  896);
      g.s[1] = mk(msg2 + 896,  wtC21, z10,  nullptr, 1536, 768);
      g.s[2] = mk(msg2 + 1664, wtC21, z11,  nullptr, 1536, 768);
      g.s[3] = mk(msg2 + 2432, wtC22, z20,  nullptr, 1280, 640);
      g.s[4] = mk(msg2 + 3072, wtC22, z21,  nullptr, 1280, 640);
      g.nwg = b;
      k_gemm_seg<<<b, 256, 0, stream>>>(g);
    }

    k_recomb2<<<cm, 128, 0, stream>>>(m3x0, z10, z11, z20, z21, env, msg3T, perm, e0);

    // wigner inverse + run-gather scatter (MFMA)
    k_wig_inv<<<cm, 256, 0, stream>>>(msg3T, wig_inv, eidx, out, perm, e0, cm);
  }
}